// Round 4
// baseline (372.029 us; speedup 1.0000x reference)
//
#include <hip/hip_runtime.h>
#include <hip/hip_bf16.h>

// ---------------------------------------------------------------------------
// DeepCut fused pipeline. B=4, T=4096 (64x64), D=384, K=8, CH=64, NL=4.
// Graph = 5x5 box stencil with separable D^-1/2 normalization u(i)*u(j).
// Edge-conv uses bf16 MFMA (loss-only path; S stays fp32).
// ---------------------------------------------------------------------------

#define B_ 4
#define T_ 4096
#define D_ 384
#define K_ 8
#define CH_ 64

typedef __attribute__((ext_vector_type(8))) short short8b;
typedef __attribute__((ext_vector_type(4))) float f32x4;

__device__ __forceinline__ float wred(float v) {
#pragma unroll
  for (int off = 32; off > 0; off >>= 1) v += __shfl_xor(v, off);
  return v;
}

__device__ __forceinline__ short bf16rne(float f) {
  unsigned u = __float_as_uint(f);
  unsigned r = (u + 0x7FFFu + ((u >> 16) & 1u)) >> 16;
  return (short)r;
}

// u(i) = rsqrt(#valid offsets in [-2,2] along one axis)
__device__ __forceinline__ float uval(int i) {
  int c = (i < 2 ? i : 2) + ((63 - i) < 2 ? (63 - i) : 2) + 1;
  return rsqrtf((float)c);
}

// ---- transpose ec_w1 (32,384,3,3) -> wq[q][o][d] bf16, q=ky*3+kx; zero acc ----
__global__ void k_wq(const float* __restrict__ w, short* __restrict__ wq,
                     float* __restrict__ accg) {
  if (blockIdx.x == 0) {
    accg[threadIdx.x] = 0.f;
    accg[threadIdx.x + 256] = 0.f;
  }
  int idx = blockIdx.x * 256 + threadIdx.x;
  if (idx >= 32 * 384 * 9) return;
  int q = idx % 9;
  int rest = idx / 9;
  int d = rest % 384;
  int o = rest / 384;
  wq[((size_t)(q * 32 + o)) * 384 + d] = bf16rne(w[idx]);
}

// ---- layer-0 GEMM, register-tiled: 32 rows/block, thread = 8 rows x 1 col ----
// xw = [feat,pos]@W0 ; res = LN([feat,pos]@res_w + res_b)
__global__ __launch_bounds__(256) void k_gemm0(
    const float* __restrict__ feat, const float* __restrict__ w0,
    const float* __restrict__ resw, const float* __restrict__ resb,
    const float* __restrict__ resg, const float* __restrict__ reslb,
    float* __restrict__ xw, float* __restrict__ res) {
  __shared__ float sf[32 * 384];   // 48KB feature tile
  __shared__ float sw[32 * 128];   // 16KB weight chunk (w0 | resw interleaved)
  int tid = threadIdx.x;
  int row0 = blockIdx.x * 32;
  const float4* f4 = (const float4*)(feat + (size_t)row0 * D_);
  float4* sf4 = (float4*)sf;
#pragma unroll
  for (int l = 0; l < 12; ++l) sf4[tid + l * 256] = f4[tid + l * 256];
  int c = tid & 63, rg = tid >> 6;
  float a1[8], a2[8];
#pragma unroll
  for (int m = 0; m < 8; ++m) { a1[m] = 0.f; a2[m] = 0.f; }
  for (int cc = 0; cc < 12; ++cc) {
    __syncthreads();
#pragma unroll
    for (int l = 0; l < 8; ++l) {
      int kk = (tid >> 6) + l * 4;
      int c2 = tid & 63;
      sw[kk * 128 + c2] = w0[(cc * 32 + kk) * 64 + c2];
      sw[kk * 128 + 64 + c2] = resw[(cc * 32 + kk) * 64 + c2];
    }
    __syncthreads();
    const float* sfb = sf + rg * 8 * 384 + cc * 32;
#pragma unroll
    for (int kq = 0; kq < 8; ++kq) {
      float4 fv[8];
#pragma unroll
      for (int m = 0; m < 8; ++m)
        fv[m] = *(const float4*)&sfb[m * 384 + kq * 4];
#pragma unroll
      for (int dk = 0; dk < 4; ++dk) {
        float w0v = sw[(kq * 4 + dk) * 128 + c];
        float w2v = sw[(kq * 4 + dk) * 128 + 64 + c];
#pragma unroll
        for (int m = 0; m < 8; ++m) {
          float f = ((const float*)&fv[m])[dk];
          a1[m] = fmaf(f, w0v, a1[m]);
          a2[m] = fmaf(f, w2v, a2[m]);
        }
      }
    }
  }
  // pos columns (k=384,385) + biases, then per-row LN on a2
  float wpx0 = w0[384 * 64 + c], wpy0 = w0[385 * 64 + c];
  float wpx2 = resw[384 * 64 + c], wpy2 = resw[385 * 64 + c];
  float rb = resb[c], rg_ = resg[c], rlb = reslb[c];
#pragma unroll
  for (int m = 0; m < 8; ++m) {
    int row = row0 + rg * 8 + m;
    int t = row & (T_ - 1);
    float px = (float)(t & 63) * (1.0f / 63.0f);
    float py = (float)(t >> 6) * (1.0f / 63.0f);
    float v1 = a1[m] + px * wpx0 + py * wpy0;
    float v2 = a2[m] + px * wpx2 + py * wpy2 + rb;
    xw[(size_t)row * 64 + c] = v1;
    float mean = wred(v2) * (1.f / 64.f);
    float d = v2 - mean;
    float var = wred(d * d) * (1.f / 64.f);
    res[(size_t)row * 64 + c] = d * rsqrtf(var + 1e-5f) * rg_ + rlb;
  }
}

// ---- 64->64 GEMM, register-tiled: 32 rows/block, thread = 8 rows x 1 col ----
__global__ __launch_bounds__(256) void k_gemm64(const float* __restrict__ X,
                                                const float* __restrict__ W,
                                                float* __restrict__ Y) {
  __shared__ float sf[32 * 64];   // 8KB
  __shared__ float sW[64 * 64];   // 16KB
  int tid = threadIdx.x;
  size_t base = (size_t)blockIdx.x * 2048;
  const float4* x4 = (const float4*)(X + base);
  float4* sf4 = (float4*)sf;
#pragma unroll
  for (int l = 0; l < 2; ++l) sf4[tid + l * 256] = x4[tid + l * 256];
  const float4* w4 = (const float4*)W;
  float4* sW4 = (float4*)sW;
#pragma unroll
  for (int l = 0; l < 4; ++l) sW4[tid + l * 256] = w4[tid + l * 256];
  __syncthreads();
  int c = tid & 63, rg = tid >> 6;
  float a[8];
#pragma unroll
  for (int m = 0; m < 8; ++m) a[m] = 0.f;
  const float4* sfb = (const float4*)(sf + rg * 8 * 64);
#pragma unroll
  for (int kq = 0; kq < 16; ++kq) {
    float4 fv[8];
#pragma unroll
    for (int m = 0; m < 8; ++m) fv[m] = sfb[m * 16 + kq];
#pragma unroll
    for (int dk = 0; dk < 4; ++dk) {
      float wv = sW[(kq * 4 + dk) * 64 + c];
#pragma unroll
      for (int m = 0; m < 8; ++m)
        a[m] = fmaf(((const float*)&fv[m])[dk], wv, a[m]);
    }
  }
#pragma unroll
  for (int m = 0; m < 8; ++m)
    Y[base + (size_t)(rg * 8 + m) * 64 + c] = a[m];
}

// ---- stencil + bias + LN + ELU + residual ----
__global__ __launch_bounds__(256) void k_stencil(
    const float* __restrict__ xw, const float* __restrict__ bias,
    const float* __restrict__ lng, const float* __restrict__ lnb,
    const float* __restrict__ resid, float* __restrict__ xout) {
  int r = threadIdx.x >> 6, c = threadIdx.x & 63;
  int row = blockIdx.x * 4 + r;
  int b = row >> 12, t = row & (T_ - 1);
  int i = t >> 6, j = t & 63;
  float ui = uval(i), uj = uval(j);
  float s = 0.f;
#pragma unroll
  for (int di = -2; di <= 2; ++di) {
    int ii = i + di;
    if (ii < 0 || ii > 63) continue;
    float wi = uval(ii);
#pragma unroll
    for (int dj = -2; dj <= 2; ++dj) {
      int jj = j + dj;
      if (jj < 0 || jj > 63) continue;
      s = fmaf(wi * uval(jj), xw[((size_t)((b << 12) + (ii << 6) + jj)) * 64 + c], s);
    }
  }
  float h = ui * uj * s + bias[c];
  float m = wred(h) * (1.f / 64.f);
  float d = h - m;
  float v = wred(d * d) * (1.f / 64.f);
  float n = d * rsqrtf(v + 1e-5f) * lng[c] + lnb[c];
  float e = n > 0.f ? n : (expf(n) - 1.f);
  xout[(size_t)row * 64 + c] = e + resid[(size_t)row * 64 + c];
}

// ---- MLP head: h1 = elu(LN(x@w1+b1)); S = softmax(h1@w2+b2); also writes Sp ----
__global__ __launch_bounds__(256) void k_mlp(
    const float* __restrict__ X, const float* __restrict__ w1,
    const float* __restrict__ b1, const float* __restrict__ lng,
    const float* __restrict__ lnb, const float* __restrict__ w2,
    const float* __restrict__ b2, float* __restrict__ S, float* __restrict__ Sp) {
  int r = threadIdx.x >> 6, lane = threadIdx.x & 63;
  size_t row = (size_t)blockIdx.x * 4 + r;
  float xv = X[row * 64 + lane];
  float a = b1[lane];
#pragma unroll
  for (int k = 0; k < 64; ++k) {
    float xk = __shfl(xv, k);
    a = fmaf(xk, w1[k * 64 + lane], a);
  }
  float m = wred(a) * (1.f / 64.f);
  float d = a - m;
  float v = wred(d * d) * (1.f / 64.f);
  float h = d * rsqrtf(v + 1e-5f) * lng[lane] + lnb[lane];
  h = h > 0.f ? h : (expf(h) - 1.f);
  float lg0 = wred(h * w2[lane * 8 + 0]) + b2[0];
  float lg1 = wred(h * w2[lane * 8 + 1]) + b2[1];
  float lg2 = wred(h * w2[lane * 8 + 2]) + b2[2];
  float lg3 = wred(h * w2[lane * 8 + 3]) + b2[3];
  float lg4 = wred(h * w2[lane * 8 + 4]) + b2[4];
  float lg5 = wred(h * w2[lane * 8 + 5]) + b2[5];
  float lg6 = wred(h * w2[lane * 8 + 6]) + b2[6];
  float lg7 = wred(h * w2[lane * 8 + 7]) + b2[7];
  float mx = fmaxf(fmaxf(fmaxf(lg0, lg1), fmaxf(lg2, lg3)),
                   fmaxf(fmaxf(lg4, lg5), fmaxf(lg6, lg7)));
  lg0 = expf(lg0 - mx); lg1 = expf(lg1 - mx); lg2 = expf(lg2 - mx);
  lg3 = expf(lg3 - mx); lg4 = expf(lg4 - mx); lg5 = expf(lg5 - mx);
  lg6 = expf(lg6 - mx); lg7 = expf(lg7 - mx);
  float inv = 1.f / (lg0 + lg1 + lg2 + lg3 + lg4 + lg5 + lg6 + lg7);
  if (lane < 8) {
    float val = lane == 0 ? lg0 : lane == 1 ? lg1 : lane == 2 ? lg2 :
                lane == 3 ? lg3 : lane == 4 ? lg4 : lane == 5 ? lg5 :
                lane == 6 ? lg6 : lg7;
    val *= inv;
    int b = (int)(row >> 12), t = (int)(row & (T_ - 1));
    S[row * 8 + lane] = val;
    Sp[((size_t)((b << 3) + lane) << 12) + t] = val;
  }
}

// ---- merged normalized-cut (blocks 0..511) + SS (blocks 0..31 extra) ----
__global__ __launch_bounds__(256) void k_cutss(const float* __restrict__ S,
                                               float* __restrict__ accg) {
  {
    int k = threadIdx.x & 7;
    int tl = threadIdx.x >> 3;
    int gid = blockIdx.x * 32 + tl;
    int b = gid >> 12, t = gid & (T_ - 1);
    int i = t >> 6, j = t & 63;
    float ui = uval(i), uj = uval(j);
    float as = 0.f, sui = 0.f, suj = 0.f;
#pragma unroll
    for (int di = -2; di <= 2; ++di) {
      int ii = i + di;
      if (ii < 0 || ii > 63) continue;
      float wi = uval(ii);
      sui += wi;
#pragma unroll
      for (int dj = -2; dj <= 2; ++dj) {
        int jj = j + dj;
        if (jj < 0 || jj > 63) continue;
        as = fmaf(wi * uval(jj),
                  S[((size_t)((b << 12) + (ii << 6) + jj)) * 8 + k], as);
      }
    }
#pragma unroll
    for (int dj = -2; dj <= 2; ++dj) {
      int jj = j + dj;
      if (jj >= 0 && jj <= 63) suj += uval(jj);
    }
    as *= ui * uj;
    float sv = S[(size_t)gid * 8 + k];
    float degA = ui * uj * sui * suj;
    float numv = wred(sv * as);
    float denv = wred(sv * sv * degA);
    __shared__ float lds[8];
    int wid = threadIdx.x >> 6, lane = threadIdx.x & 63;
    if (lane == 0) { lds[wid * 2] = numv; lds[wid * 2 + 1] = denv; }
    __syncthreads();
    if (threadIdx.x == 0) {
      atomicAdd(&accg[0 + b], lds[0] + lds[2] + lds[4] + lds[6]);
      atomicAdd(&accg[4 + b], lds[1] + lds[3] + lds[5] + lds[7]);
    }
  }
  if (blockIdx.x < 32) {
    int b = blockIdx.x >> 3, chunk = blockIdx.x & 7;
    int wid = threadIdx.x >> 6, lane = threadIdx.x & 63;
    int kk = lane >> 3, ll = lane & 7;
    int t0 = chunk * 512 + wid * 128;
    float a = 0.f;
    const float* Sb = S + ((size_t)b << 12) * 8;
    for (int it = 0; it < 128; ++it) {
      const float* sr = Sb + (size_t)(t0 + it) * 8;
      a = fmaf(sr[kk], sr[ll], a);
    }
    __shared__ float lds2[256];
    lds2[threadIdx.x] = a;
    __syncthreads();
    if (threadIdx.x < 64) {
      float s = lds2[threadIdx.x] + lds2[threadIdx.x + 64] +
                lds2[threadIdx.x + 128] + lds2[threadIdx.x + 192];
      atomicAdd(&accg[80 + b * 64 + threadIdx.x], s);
    }
  }
}

// ---- spatial smoothness: per (b,k) plane, 2x depthwise conv3x3 + per-plane GN ----
__global__ __launch_bounds__(256) void k_sm(
    const float* __restrict__ Sp, const float* __restrict__ w1,
    const float* __restrict__ b1, const float* __restrict__ g1,
    const float* __restrict__ bb1, const float* __restrict__ w2,
    const float* __restrict__ b2, const float* __restrict__ g2,
    const float* __restrict__ bb2, float* __restrict__ accg) {
  __shared__ float p0[4096];
  __shared__ float p1[4096];
  __shared__ float red[8];
  int bk = blockIdx.x, b = bk >> 3, k = bk & 7;
  const float4* src = (const float4*)(Sp + (size_t)bk * 4096);
  float4* d0 = (float4*)p0;
  for (int i = threadIdx.x; i < 1024; i += 256) d0[i] = src[i];
  float W1[9], W2[9];
#pragma unroll
  for (int q = 0; q < 9; ++q) { W1[q] = w1[k * 9 + q]; W2[q] = w2[k * 9 + q]; }
  __syncthreads();
  int wid = threadIdx.x >> 6, lane = threadIdx.x & 63;
  float y[16];
  float s1 = 0.f, s2 = 0.f;
#pragma unroll
  for (int v = 0; v < 16; ++v) {
    int p = v * 256 + threadIdx.x;
    int i = p >> 6, j = p & 63;
    float a = b1[k];
#pragma unroll
    for (int dy = 0; dy < 3; ++dy) {
      int ii = i + dy - 1;
      if (ii < 0 || ii > 63) continue;
#pragma unroll
      for (int dx = 0; dx < 3; ++dx) {
        int jj = j + dx - 1;
        if (jj < 0 || jj > 63) continue;
        a = fmaf(W1[dy * 3 + dx], p0[(ii << 6) + jj], a);
      }
    }
    y[v] = a;
    s1 += a;
    s2 = fmaf(a, a, s2);
  }
  s1 = wred(s1); s2 = wred(s2);
  if (lane == 0) { red[wid * 2] = s1; red[wid * 2 + 1] = s2; }
  __syncthreads();
  float mean = (red[0] + red[2] + red[4] + red[6]) * (1.f / 4096.f);
  float var = (red[1] + red[3] + red[5] + red[7]) * (1.f / 4096.f) - mean * mean;
  float inv = rsqrtf(var + 1e-5f) * g1[k];
  float sh = bb1[k];
  __syncthreads();
#pragma unroll
  for (int v = 0; v < 16; ++v) {
    int p = v * 256 + threadIdx.x;
    p1[p] = fmaxf((y[v] - mean) * inv + sh, 0.f);
  }
  __syncthreads();
  s1 = 0.f; s2 = 0.f;
#pragma unroll
  for (int v = 0; v < 16; ++v) {
    int p = v * 256 + threadIdx.x;
    int i = p >> 6, j = p & 63;
    float a = b2[k];
#pragma unroll
    for (int dy = 0; dy < 3; ++dy) {
      int ii = i + dy - 1;
      if (ii < 0 || ii > 63) continue;
#pragma unroll
      for (int dx = 0; dx < 3; ++dx) {
        int jj = j + dx - 1;
        if (jj < 0 || jj > 63) continue;
        a = fmaf(W2[dy * 3 + dx], p1[(ii << 6) + jj], a);
      }
    }
    y[v] = a;
    s1 += a;
    s2 = fmaf(a, a, s2);
  }
  s1 = wred(s1); s2 = wred(s2);
  if (lane == 0) { red[wid * 2] = s1; red[wid * 2 + 1] = s2; }
  __syncthreads();
  float mean2 = (red[0] + red[2] + red[4] + red[6]) * (1.f / 4096.f);
  float var2 = (red[1] + red[3] + red[5] + red[7]) * (1.f / 4096.f) - mean2 * mean2;
  float inv2 = rsqrtf(var2 + 1e-5f) * g2[k];
  float sh2 = bb2[k];
  float sd = 0.f;
#pragma unroll
  for (int v = 0; v < 16; ++v) {
    int p = v * 256 + threadIdx.x;
    float sm = (y[v] - mean2) * inv2 + sh2;
    float dd = sm - p0[p];
    sd = fmaf(dd, dd, sd);
  }
  sd = wred(sd);
  __syncthreads();
  if (lane == 0) red[wid] = sd;
  __syncthreads();
  if (threadIdx.x == 0)
    atomicAdd(&accg[8 + b], (red[0] + red[1] + red[2] + red[3]) * (1.f / 32768.f));
}

// ---- edge conv via bf16 MFMA: block = image row, 64px x 32ch, K'=9*384 ----
__global__ __launch_bounds__(256) void k_ecconv(
    const float* __restrict__ feat, const short* __restrict__ wq,
    const float* __restrict__ bias1, float* __restrict__ eraw,
    float* __restrict__ accg) {
  __shared__ __align__(16) short Abuf[3 * 67 * 32];  // [r][px slot 0..66][32d]
  __shared__ __align__(16) short Wbuf[9 * 32 * 32];  // [q][o][32d]
  __shared__ float sW1[4][32], sW2[4][32];
  int blk = blockIdx.x;
  int b = blk >> 6, i = blk & 63;
  int tid = threadIdx.x;
  int wid = tid >> 6, lane = tid & 63;
  int m = lane & 15, kg = lane >> 4;
  if (tid < 36) {
    int zkg = tid & 3, sl = (tid >> 2) % 3, r = tid / 12;
    int slot = sl == 0 ? 0 : (sl == 1 ? 65 : 66);
    *(short8b*)&Abuf[(r * 67 + slot) * 32 + zkg * 8] = (short8b)0;
  }
  f32x4 acc0 = {0.f, 0.f, 0.f, 0.f};
  f32x4 acc1 = {0.f, 0.f, 0.f, 0.f};
  int abase = (wid * 16 + m) * 32 + kg * 8;
  int bbase = m * 32 + kg * 8;
  for (int c = 0; c < 12; ++c) {
    __syncthreads();
#pragma unroll
    for (int s = 0; s < 3; ++s) {
      int cid = tid + (s << 8);
      int akg = cid & 3, px = (cid >> 2) & 63, r = cid >> 8;
      int ii = i + r - 1;
      short8b v = (short8b)0;
      if (ii >= 0 && ii < 64) {
        const float* src =
            feat + ((size_t)((b << 12) + (ii << 6) + px)) * D_ + c * 32 + akg * 8;
        float4 f0 = *(const float4*)src;
        float4 f1 = *(const float4*)(src + 4);
        v[0] = bf16rne(f0.x); v[1] = bf16rne(f0.y);
        v[2] = bf16rne(f0.z); v[3] = bf16rne(f0.w);
        v[4] = bf16rne(f1.x); v[5] = bf16rne(f1.y);
        v[6] = bf16rne(f1.z); v[7] = bf16rne(f1.w);
      }
      *(short8b*)&Abuf[(r * 67 + px + 1) * 32 + akg * 8] = v;
    }
    for (int l = tid; l < 1152; l += 256) {
      int wkg = l & 3, oo = (l >> 2) & 31, q = l >> 7;
      short8b wv =
          *(const short8b*)(wq + ((size_t)(q * 32 + oo)) * D_ + c * 32 + wkg * 8);
      *(short8b*)&Wbuf[(q * 32 + oo) * 32 + wkg * 8] = wv;
    }
    __syncthreads();
#pragma unroll
    for (int q = 0; q < 9; ++q) {
      short8b av = *(const short8b*)&Abuf[abase + ((q / 3) * 67 + (q % 3)) * 32];
      short8b bv0 = *(const short8b*)&Wbuf[bbase + q * 1024];
      short8b bv1 = *(const short8b*)&Wbuf[bbase + q * 1024 + 512];
      acc0 = __builtin_amdgcn_mfma_f32_16x16x32_bf16(av, bv0, acc0, 0, 0, 0);
      acc1 = __builtin_amdgcn_mfma_f32_16x16x32_bf16(av, bv1, acc1, 0, 0, 0);
    }
  }
  int o0 = m, o1 = 16 + m;
  float bs0 = bias1[o0], bs1 = bias1[o1];
  float s1a = 0.f, s2a = 0.f, s1b = 0.f, s2b = 0.f;
  int jbase = wid * 16 + kg * 4;
#pragma unroll
  for (int rg = 0; rg < 4; ++rg) {
    float v0 = acc0[rg] + bs0;
    float v1 = acc1[rg] + bs1;
    int j = jbase + rg;
    size_t px = ((size_t)((b << 12) + (i << 6) + j)) * 32;
    eraw[px + o0] = v0;
    eraw[px + o1] = v1;
    s1a += v0; s2a = fmaf(v0, v0, s2a);
    s1b += v1; s2b = fmaf(v1, v1, s2b);
  }
  s1a += __shfl_xor(s1a, 16); s1a += __shfl_xor(s1a, 32);
  s2a += __shfl_xor(s2a, 16); s2a += __shfl_xor(s2a, 32);
  s1b += __shfl_xor(s1b, 16); s1b += __shfl_xor(s1b, 32);
  s2b += __shfl_xor(s2b, 16); s2b += __shfl_xor(s2b, 32);
  if (lane < 16) {
    sW1[wid][lane] = s1a; sW2[wid][lane] = s2a;
    sW1[wid][lane + 16] = s1b; sW2[wid][lane + 16] = s2b;
  }
  __syncthreads();
  if (tid < 32) {
    float t1 = sW1[0][tid] + sW1[1][tid] + sW1[2][tid] + sW1[3][tid];
    float t2 = sW2[0][tid] + sW2[1][tid] + sW2[2][tid] + sW2[3][tid];
    t1 += __shfl_xor(t1, 1); t1 += __shfl_xor(t1, 2);
    t2 += __shfl_xor(t2, 1); t2 += __shfl_xor(t2, 2);
    if ((tid & 3) == 0) {
      atomicAdd(&accg[16 + b * 16 + (tid >> 2) * 2], t1);
      atomicAdd(&accg[16 + b * 16 + (tid >> 2) * 2 + 1], t2);
    }
  }
}

// ---- GN + relu + 1x1 conv + sigmoid -> ew (B,T); eraw pixel-major [b][t][32]
__global__ __launch_bounds__(256) void k_ecfinal(
    const float* __restrict__ eraw, const float* __restrict__ accg,
    const float* __restrict__ gng, const float* __restrict__ gnb,
    const float* __restrict__ w2, const float* __restrict__ b2,
    float* __restrict__ ew) {
  __shared__ float st[16];
  int idx = blockIdx.x * 256 + threadIdx.x;
  int b = idx >> 12;
  if (threadIdx.x < 16) st[threadIdx.x] = accg[16 + b * 16 + threadIdx.x];
  __syncthreads();
  float a = b2[0];
  const float4* er = (const float4*)(eraw + (size_t)idx * 32);
#pragma unroll
  for (int oq = 0; oq < 8; ++oq) {
    float mean = st[oq * 2] * (1.f / 16384.f);
    float var = st[oq * 2 + 1] * (1.f / 16384.f) - mean * mean;
    float inv = rsqrtf(var + 1e-5f);
    float4 e = er[oq];
    int o = oq * 4;
    float v0 = (e.x - mean) * inv * gng[o + 0] + gnb[o + 0];
    float v1 = (e.y - mean) * inv * gng[o + 1] + gnb[o + 1];
    float v2 = (e.z - mean) * inv * gng[o + 2] + gnb[o + 2];
    float v3 = (e.w - mean) * inv * gng[o + 3] + gnb[o + 3];
    a = fmaf(fmaxf(v0, 0.f), w2[o + 0], a);
    a = fmaf(fmaxf(v1, 0.f), w2[o + 1], a);
    a = fmaf(fmaxf(v2, 0.f), w2[o + 2], a);
    a = fmaf(fmaxf(v3, 0.f), w2[o + 3], a);
  }
  ew[idx] = 1.f / (1.f + expf(-a));
}

// ---- feature-smoothness gradient sums ----
__global__ __launch_bounds__(256) void k_fsloss(const float* __restrict__ feat,
                                                const float* __restrict__ ew,
                                                float* __restrict__ accg) {
  float sy = 0.f, sx = 0.f;
  const int N = B_ * T_ * 96;
  for (int idx = blockIdx.x * 256 + threadIdx.x; idx < N; idx += gridDim.x * 256) {
    int d4 = idx % 96;
    int rt = idx / 96;
    int t = rt & (T_ - 1);
    int i = t >> 6, j = t & 63;
    const float4* fp = (const float4*)(feat + (size_t)rt * D_) + d4;
    float4 f0 = *fp;
    if (i < 63) {
      float4 f1 = fp[64 * 96];
      float w = ew[rt + 64];
      float a = f1.x - f0.x, bq = f1.y - f0.y, c = f1.z - f0.z, d = f1.w - f0.w;
      sy += w * (a * a + bq * bq + c * c + d * d);
    }
    if (j < 63) {
      float4 f1 = fp[96];
      float w = ew[rt + 1];
      float a = f1.x - f0.x, bq = f1.y - f0.y, c = f1.z - f0.z, d = f1.w - f0.w;
      sx += w * (a * a + bq * bq + c * c + d * d);
    }
  }
  sy = wred(sy);
  sx = wred(sx);
  __shared__ float lds[8];
  int wid = threadIdx.x >> 6, lane = threadIdx.x & 63;
  if (lane == 0) { lds[wid * 2] = sy; lds[wid * 2 + 1] = sx; }
  __syncthreads();
  if (threadIdx.x == 0) {
    atomicAdd(&accg[12], lds[0] + lds[2] + lds[4] + lds[6]);
    atomicAdd(&accg[13], lds[1] + lds[3] + lds[5] + lds[7]);
  }
}

// ---- final scalar assembly ----
__global__ void k_final(const float* __restrict__ accg, float* __restrict__ out) {
  if (threadIdx.x != 0 || blockIdx.x != 0) return;
  float total = 0.f;
  for (int b = 0; b < 4; ++b) {
    const float* SSb = accg + 80 + b * 64;
    float ssq = 0.f;
    for (int v = 0; v < 64; ++v) ssq += SSb[v] * SSb[v];
    float ssn = sqrtf(ssq);
    float tgt = 1.f / (sqrtf(8.f) + 1e-6f);
    float inv = 1.f / (ssn + 1e-6f);
    float lo = 0.f;
    for (int kk = 0; kk < 8; ++kk)
      for (int ll = 0; ll < 8; ++ll) {
        float dd = SSb[kk * 8 + ll] * inv - (kk == ll ? tgt : 0.f);
        lo += dd * dd;
      }
    lo = sqrtf(lo);
    float lc = -accg[b] / (accg[4 + b] + 1e-6f);
    total += lc + lo + 0.01f * accg[8 + b];
  }
  total *= 0.25f;
  const float cnt = 4.f * 384.f * 63.f * 64.f;
  float ly = accg[12] / cnt * (1.f / 384.f);
  float lx = accg[13] / cnt * (1.f / 384.f);
  out[131072] = total + 0.09f * 0.5f * (ly + lx);
}

extern "C" void kernel_launch(void* const* d_in, const int* in_sizes, int n_in,
                              void* d_out, int out_size, void* d_ws, size_t ws_size,
                              hipStream_t stream) {
  const float* feat = (const float*)d_in[0];
  const float* gcn_w0 = (const float*)d_in[1];
  const float* gcn_b0 = (const float*)d_in[2];
  const float* gcn_w = (const float*)d_in[3];
  const float* gcn_b = (const float*)d_in[4];
  const float* ln_g = (const float*)d_in[5];
  const float* ln_b = (const float*)d_in[6];
  const float* res_w = (const float*)d_in[7];
  const float* res_b = (const float*)d_in[8];
  const float* res_ln_g = (const float*)d_in[9];
  const float* res_ln_b = (const float*)d_in[10];
  const float* mlp_w1 = (const float*)d_in[11];
  const float* mlp_b1 = (const float*)d_in[12];
  const float* mlp_ln_g = (const float*)d_in[13];
  const float* mlp_ln_b = (const float*)d_in[14];
  const float* mlp_w2 = (const float*)d_in[15];
  const float* mlp_b2 = (const float*)d_in[16];
  const float* sm_w1 = (const float*)d_in[17];
  const float* sm_b1 = (const float*)d_in[18];
  const float* sm_g1 = (const float*)d_in[19];
  const float* sm_bb1 = (const float*)d_in[20];
  const float* sm_w2 = (const float*)d_in[21];
  const float* sm_b2 = (const float*)d_in[22];
  const float* sm_g2 = (const float*)d_in[23];
  const float* sm_bb2 = (const float*)d_in[24];
  const float* ec_w1 = (const float*)d_in[25];
  const float* ec_b1 = (const float*)d_in[26];
  const float* ec_gn_g = (const float*)d_in[27];
  const float* ec_gn_b = (const float*)d_in[28];
  const float* ec_w2 = (const float*)d_in[29];
  const float* ec_b2 = (const float*)d_in[30];

  float* out = (float*)d_out;
  float* ws = (float*)d_ws;
  float* acc = ws;                       // 512 floats
  float* xw = ws + 512;                  // B*T*64
  float* xbuf = xw + 1048576;            // B*T*64
  float* resbuf = xbuf + 1048576;        // B*T*64
  float* Sp = resbuf + 1048576;          // B*K*T
  float* eraw = Sp + 131072;             // B*T*32 (pixel-major)
  float* ew = eraw + 524288;             // B*T
  short* wqb = (short*)(ew + 16384);     // 110592 shorts (bf16)
  float* S = out;                        // (B,T,K) straight into d_out

  k_wq<<<(110592 + 255) / 256, 256, 0, stream>>>(ec_w1, wqb, acc);

  k_gemm0<<<B_ * T_ / 32, 256, 0, stream>>>(feat, gcn_w0, res_w, res_b, res_ln_g,
                                            res_ln_b, xw, resbuf);
  k_stencil<<<B_ * T_ / 4, 256, 0, stream>>>(xw, gcn_b0, ln_g, ln_b, resbuf, xbuf);
  for (int i = 1; i < 4; ++i) {
    k_gemm64<<<B_ * T_ / 32, 256, 0, stream>>>(xbuf, gcn_w + (i - 1) * 4096, xw);
    k_stencil<<<B_ * T_ / 4, 256, 0, stream>>>(xw, gcn_b + (i - 1) * 64,
                                               ln_g + i * 64, ln_b + i * 64, xbuf,
                                               xbuf);
  }
  k_mlp<<<B_ * T_ / 4, 256, 0, stream>>>(xbuf, mlp_w1, mlp_b1, mlp_ln_g, mlp_ln_b,
                                         mlp_w2, mlp_b2, S, Sp);

  k_cutss<<<B_ * T_ / 32, 256, 0, stream>>>(S, acc);
  k_sm<<<32, 256, 0, stream>>>(Sp, sm_w1, sm_b1, sm_g1, sm_bb1, sm_w2, sm_b2, sm_g2,
                               sm_bb2, acc);

  k_ecconv<<<256, 256, 0, stream>>>(feat, wqb, ec_b1, eraw, acc);
  k_ecfinal<<<B_ * T_ / 256, 256, 0, stream>>>(eraw, acc, ec_gn_g, ec_gn_b, ec_w2,
                                               ec_b2, ew);
  k_fsloss<<<2048, 256, 0, stream>>>(feat, ew, acc);
  k_final<<<1, 64, 0, stream>>>(acc, out);
}

// Round 5
// 274.479 us; speedup vs baseline: 1.3554x; 1.3554x over previous
//
#include <hip/hip_runtime.h>
#include <hip/hip_bf16.h>

// ---------------------------------------------------------------------------
// DeepCut fused pipeline. B=4, T=4096 (64x64), D=384, K=8, CH=64, NL=4.
// Graph = 5x5 box stencil with separable D^-1/2 normalization u(i)*u(j).
// gemm0 + edge-conv use bf16 MFMA; LN/softmax/losses stay fp32.
// ---------------------------------------------------------------------------

#define B_ 4
#define T_ 4096
#define D_ 384
#define K_ 8
#define CH_ 64

typedef __attribute__((ext_vector_type(8))) short short8b;
typedef __attribute__((ext_vector_type(4))) float f32x4;

__device__ __forceinline__ float wred(float v) {
#pragma unroll
  for (int off = 32; off > 0; off >>= 1) v += __shfl_xor(v, off);
  return v;
}

__device__ __forceinline__ short bf16rne(float f) {
  unsigned u = __float_as_uint(f);
  unsigned r = (u + 0x7FFFu + ((u >> 16) & 1u)) >> 16;
  return (short)r;
}

__device__ __forceinline__ float bf2f(short s) {
  return __uint_as_float(((unsigned)(unsigned short)s) << 16);
}

// u(i) = rsqrt(#valid offsets in [-2,2] along one axis)
__device__ __forceinline__ float uval(int i) {
  int c = (i < 2 ? i : 2) + ((63 - i) < 2 ? (63 - i) : 2) + 1;
  return rsqrtf((float)c);
}

// ---- feat fp32 -> bf16 (B*T*384) ----
__global__ __launch_bounds__(256) void k_featbf(const float* __restrict__ feat,
                                                short* __restrict__ fb) {
  int tid = blockIdx.x * 256 + threadIdx.x;  // one per 8 elems; grid 3072
  const float4* s = (const float4*)feat + (size_t)tid * 2;
  float4 a = s[0], b = s[1];
  short8b v;
  v[0] = bf16rne(a.x); v[1] = bf16rne(a.y); v[2] = bf16rne(a.z); v[3] = bf16rne(a.w);
  v[4] = bf16rne(b.x); v[5] = bf16rne(b.y); v[6] = bf16rne(b.z); v[7] = bf16rne(b.w);
  *(short8b*)(fb + (size_t)tid * 8) = v;
}

// ---- transpose ec_w1 (32,384,3,3) -> wq[q][o][d] bf16; zero acc ----
__global__ void k_wq(const float* __restrict__ w, short* __restrict__ wq,
                     float* __restrict__ accg) {
  if (blockIdx.x == 0) {
    accg[threadIdx.x] = 0.f;
    accg[threadIdx.x + 256] = 0.f;
  }
  int idx = blockIdx.x * 256 + threadIdx.x;
  if (idx >= 32 * 384 * 9) return;
  int q = idx % 9;
  int rest = idx / 9;
  int d = rest % 384;
  int o = rest / 384;
  wq[((size_t)(q * 32 + o)) * 384 + d] = bf16rne(w[idx]);
}

// ---- B = [w0 | resw] (384 x 128) -> MFMA-fragment-ordered bf16 ----
// wb[((s*8+f)*64 + l)*8 + j] = B[k=s*32+(l>>4)*8+j][c=f*16+(l&15)]
__global__ void k_wb(const float* __restrict__ w0, const float* __restrict__ resw,
                     short* __restrict__ wb) {
  int u = blockIdx.x * 256 + threadIdx.x;  // 0..6143
  int l = u & 63, f = (u >> 6) & 7, s = u >> 9;
  int c = f * 16 + (l & 15);
  int k0 = s * 32 + ((l >> 4) << 3);
  const float* src = (c < 64) ? (w0 + c) : (resw + (c - 64));
  short8b v;
#pragma unroll
  for (int j = 0; j < 8; ++j) v[j] = bf16rne(src[(size_t)(k0 + j) * 64]);
  *(short8b*)(wb + (size_t)u * 8) = v;
}

// ---- layer-0 GEMM via bf16 MFMA: block = 64 rows x 128 cols (w0|resw), K=384
// xw = [feat,pos]@W0 (fp32 pos cols); res = LN([feat,pos]@res_w + res_b)
__global__ __launch_bounds__(256) void k_gemm0(
    const short* __restrict__ fb, const short* __restrict__ wb,
    const float* __restrict__ w0, const float* __restrict__ resw,
    const float* __restrict__ resb, const float* __restrict__ resg,
    const float* __restrict__ reslb, float* __restrict__ xw,
    float* __restrict__ res) {
  __shared__ __align__(16) short Ab[24576];  // 48KB, fragment-ordered
  __shared__ __align__(16) short Bb[49152];  // 96KB, fragment-ordered
  int tid = threadIdx.x;
  int row0 = blockIdx.x * 64;
  const short8b* wb8 = (const short8b*)wb;
  short8b* Bb8 = (short8b*)Bb;
#pragma unroll
  for (int it = 0; it < 24; ++it) Bb8[tid + it * 256] = wb8[tid + it * 256];
  short8b* Ab8 = (short8b*)Ab;
#pragma unroll
  for (int it = 0; it < 12; ++it) {
    int u = it * 256 + tid;
    int l = u & 63, w = (u >> 6) & 3, s = u >> 8;
    int row = w * 16 + (l & 15);
    int k = s * 32 + ((l >> 4) << 3);
    Ab8[u] = *(const short8b*)(fb + (size_t)(row0 + row) * 384 + k);
  }
  __syncthreads();
  int wid = tid >> 6, lane = tid & 63;
  f32x4 acc[8];
#pragma unroll
  for (int f = 0; f < 8; ++f) acc[f] = (f32x4){0.f, 0.f, 0.f, 0.f};
#pragma unroll
  for (int s = 0; s < 12; ++s) {
    short8b av = Ab8[(s * 4 + wid) * 64 + lane];
#pragma unroll
    for (int f = 0; f < 8; ++f) {
      short8b bv = Bb8[(s * 8 + f) * 64 + lane];
      acc[f] = __builtin_amdgcn_mfma_f32_16x16x32_bf16(av, bv, acc[f], 0, 0, 0);
    }
  }
  // epilogue: pos cols + bias in fp32; LN on res via 16-lane reductions
  int g = lane >> 4, ln = lane & 15;
  float pw1[4], pw2[4], rw1[4], rw2[4], rb[4], rgam[4], rbet[4];
#pragma unroll
  for (int f = 0; f < 4; ++f) {
    int c = f * 16 + ln;
    pw1[f] = w0[384 * 64 + c];  pw2[f] = w0[385 * 64 + c];
    rw1[f] = resw[384 * 64 + c]; rw2[f] = resw[385 * 64 + c];
    rb[f] = resb[c]; rgam[f] = resg[c]; rbet[f] = reslb[c];
  }
#pragma unroll
  for (int r = 0; r < 4; ++r) {
    int grow = row0 + wid * 16 + g * 4 + r;
    int t = grow & (T_ - 1);
    float px = (float)(t & 63) * (1.f / 63.f);
    float py = (float)(t >> 6) * (1.f / 63.f);
    float rv[4];
    float s1 = 0.f, s2 = 0.f;
#pragma unroll
    for (int f = 0; f < 4; ++f) {
      float xv = acc[f][r] + px * pw1[f] + py * pw2[f];
      xw[(size_t)grow * 64 + f * 16 + ln] = xv;
      float v = acc[4 + f][r] + px * rw1[f] + py * rw2[f] + rb[f];
      rv[f] = v;
      s1 += v;
      s2 = fmaf(v, v, s2);
    }
#pragma unroll
    for (int off = 1; off < 16; off <<= 1) {
      s1 += __shfl_xor(s1, off);
      s2 += __shfl_xor(s2, off);
    }
    float mean = s1 * (1.f / 64.f);
    float var = s2 * (1.f / 64.f) - mean * mean;
    float inv = rsqrtf(var + 1e-5f);
#pragma unroll
    for (int f = 0; f < 4; ++f)
      res[(size_t)grow * 64 + f * 16 + ln] = (rv[f] - mean) * inv * rgam[f] + rbet[f];
  }
}

// ---- 64->64 GEMM, register-tiled: 32 rows/block, thread = 8 rows x 1 col ----
__global__ __launch_bounds__(256) void k_gemm64(const float* __restrict__ X,
                                                const float* __restrict__ W,
                                                float* __restrict__ Y) {
  __shared__ float sf[32 * 64];   // 8KB
  __shared__ float sW[64 * 64];   // 16KB
  int tid = threadIdx.x;
  size_t base = (size_t)blockIdx.x * 2048;
  const float4* x4 = (const float4*)(X + base);
  float4* sf4 = (float4*)sf;
#pragma unroll
  for (int l = 0; l < 2; ++l) sf4[tid + l * 256] = x4[tid + l * 256];
  const float4* w4 = (const float4*)W;
  float4* sW4 = (float4*)sW;
#pragma unroll
  for (int l = 0; l < 4; ++l) sW4[tid + l * 256] = w4[tid + l * 256];
  __syncthreads();
  int c = tid & 63, rg = tid >> 6;
  float a[8];
#pragma unroll
  for (int m = 0; m < 8; ++m) a[m] = 0.f;
  const float4* sfb = (const float4*)(sf + rg * 8 * 64);
#pragma unroll
  for (int kq = 0; kq < 16; ++kq) {
    float4 fv[8];
#pragma unroll
    for (int m = 0; m < 8; ++m) fv[m] = sfb[m * 16 + kq];
#pragma unroll
    for (int dk = 0; dk < 4; ++dk) {
      float wv = sW[(kq * 4 + dk) * 64 + c];
#pragma unroll
      for (int m = 0; m < 8; ++m)
        a[m] = fmaf(((const float*)&fv[m])[dk], wv, a[m]);
    }
  }
#pragma unroll
  for (int m = 0; m < 8; ++m)
    Y[base + (size_t)(rg * 8 + m) * 64 + c] = a[m];
}

// ---- stencil + bias + LN + ELU + residual ----
__global__ __launch_bounds__(256) void k_stencil(
    const float* __restrict__ xw, const float* __restrict__ bias,
    const float* __restrict__ lng, const float* __restrict__ lnb,
    const float* __restrict__ resid, float* __restrict__ xout) {
  int r = threadIdx.x >> 6, c = threadIdx.x & 63;
  int row = blockIdx.x * 4 + r;
  int b = row >> 12, t = row & (T_ - 1);
  int i = t >> 6, j = t & 63;
  float ui = uval(i), uj = uval(j);
  float s = 0.f;
#pragma unroll
  for (int di = -2; di <= 2; ++di) {
    int ii = i + di;
    if (ii < 0 || ii > 63) continue;
    float wi = uval(ii);
#pragma unroll
    for (int dj = -2; dj <= 2; ++dj) {
      int jj = j + dj;
      if (jj < 0 || jj > 63) continue;
      s = fmaf(wi * uval(jj), xw[((size_t)((b << 12) + (ii << 6) + jj)) * 64 + c], s);
    }
  }
  float h = ui * uj * s + bias[c];
  float m = wred(h) * (1.f / 64.f);
  float d = h - m;
  float v = wred(d * d) * (1.f / 64.f);
  float n = d * rsqrtf(v + 1e-5f) * lng[c] + lnb[c];
  float e = n > 0.f ? n : (expf(n) - 1.f);
  xout[(size_t)row * 64 + c] = e + resid[(size_t)row * 64 + c];
}

// ---- MLP head: h1 = elu(LN(x@w1+b1)); S = softmax(h1@w2+b2); also writes Sp ----
__global__ __launch_bounds__(256) void k_mlp(
    const float* __restrict__ X, const float* __restrict__ w1,
    const float* __restrict__ b1, const float* __restrict__ lng,
    const float* __restrict__ lnb, const float* __restrict__ w2,
    const float* __restrict__ b2, float* __restrict__ S, float* __restrict__ Sp) {
  int r = threadIdx.x >> 6, lane = threadIdx.x & 63;
  size_t row = (size_t)blockIdx.x * 4 + r;
  float xv = X[row * 64 + lane];
  float a = b1[lane];
#pragma unroll
  for (int k = 0; k < 64; ++k) {
    float xk = __shfl(xv, k);
    a = fmaf(xk, w1[k * 64 + lane], a);
  }
  float m = wred(a) * (1.f / 64.f);
  float d = a - m;
  float v = wred(d * d) * (1.f / 64.f);
  float h = d * rsqrtf(v + 1e-5f) * lng[lane] + lnb[lane];
  h = h > 0.f ? h : (expf(h) - 1.f);
  float lg0 = wred(h * w2[lane * 8 + 0]) + b2[0];
  float lg1 = wred(h * w2[lane * 8 + 1]) + b2[1];
  float lg2 = wred(h * w2[lane * 8 + 2]) + b2[2];
  float lg3 = wred(h * w2[lane * 8 + 3]) + b2[3];
  float lg4 = wred(h * w2[lane * 8 + 4]) + b2[4];
  float lg5 = wred(h * w2[lane * 8 + 5]) + b2[5];
  float lg6 = wred(h * w2[lane * 8 + 6]) + b2[6];
  float lg7 = wred(h * w2[lane * 8 + 7]) + b2[7];
  float mx = fmaxf(fmaxf(fmaxf(lg0, lg1), fmaxf(lg2, lg3)),
                   fmaxf(fmaxf(lg4, lg5), fmaxf(lg6, lg7)));
  lg0 = expf(lg0 - mx); lg1 = expf(lg1 - mx); lg2 = expf(lg2 - mx);
  lg3 = expf(lg3 - mx); lg4 = expf(lg4 - mx); lg5 = expf(lg5 - mx);
  lg6 = expf(lg6 - mx); lg7 = expf(lg7 - mx);
  float inv = 1.f / (lg0 + lg1 + lg2 + lg3 + lg4 + lg5 + lg6 + lg7);
  if (lane < 8) {
    float val = lane == 0 ? lg0 : lane == 1 ? lg1 : lane == 2 ? lg2 :
                lane == 3 ? lg3 : lane == 4 ? lg4 : lane == 5 ? lg5 :
                lane == 6 ? lg6 : lg7;
    val *= inv;
    int b = (int)(row >> 12), t = (int)(row & (T_ - 1));
    S[row * 8 + lane] = val;
    Sp[((size_t)((b << 3) + lane) << 12) + t] = val;
  }
}

// ---- merged normalized-cut (blocks 0..511) + SS (blocks 0..31 extra) ----
__global__ __launch_bounds__(256) void k_cutss(const float* __restrict__ S,
                                               float* __restrict__ accg) {
  {
    int k = threadIdx.x & 7;
    int tl = threadIdx.x >> 3;
    int gid = blockIdx.x * 32 + tl;
    int b = gid >> 12, t = gid & (T_ - 1);
    int i = t >> 6, j = t & 63;
    float ui = uval(i), uj = uval(j);
    float as = 0.f, sui = 0.f, suj = 0.f;
#pragma unroll
    for (int di = -2; di <= 2; ++di) {
      int ii = i + di;
      if (ii < 0 || ii > 63) continue;
      float wi = uval(ii);
      sui += wi;
#pragma unroll
      for (int dj = -2; dj <= 2; ++dj) {
        int jj = j + dj;
        if (jj < 0 || jj > 63) continue;
        as = fmaf(wi * uval(jj),
                  S[((size_t)((b << 12) + (ii << 6) + jj)) * 8 + k], as);
      }
    }
#pragma unroll
    for (int dj = -2; dj <= 2; ++dj) {
      int jj = j + dj;
      if (jj >= 0 && jj <= 63) suj += uval(jj);
    }
    as *= ui * uj;
    float sv = S[(size_t)gid * 8 + k];
    float degA = ui * uj * sui * suj;
    float numv = wred(sv * as);
    float denv = wred(sv * sv * degA);
    __shared__ float lds[8];
    int wid = threadIdx.x >> 6, lane = threadIdx.x & 63;
    if (lane == 0) { lds[wid * 2] = numv; lds[wid * 2 + 1] = denv; }
    __syncthreads();
    if (threadIdx.x == 0) {
      atomicAdd(&accg[0 + b], lds[0] + lds[2] + lds[4] + lds[6]);
      atomicAdd(&accg[4 + b], lds[1] + lds[3] + lds[5] + lds[7]);
    }
  }
  if (blockIdx.x < 32) {
    int b = blockIdx.x >> 3, chunk = blockIdx.x & 7;
    int wid = threadIdx.x >> 6, lane = threadIdx.x & 63;
    int kk = lane >> 3, ll = lane & 7;
    int t0 = chunk * 512 + wid * 128;
    float a = 0.f;
    const float* Sb = S + ((size_t)b << 12) * 8;
    for (int it = 0; it < 128; ++it) {
      const float* sr = Sb + (size_t)(t0 + it) * 8;
      a = fmaf(sr[kk], sr[ll], a);
    }
    __shared__ float lds2[256];
    lds2[threadIdx.x] = a;
    __syncthreads();
    if (threadIdx.x < 64) {
      float s = lds2[threadIdx.x] + lds2[threadIdx.x + 64] +
                lds2[threadIdx.x + 128] + lds2[threadIdx.x + 192];
      atomicAdd(&accg[80 + b * 64 + threadIdx.x], s);
    }
  }
}

// ---- spatial smoothness: per (b,k) plane, 2x depthwise conv3x3 + per-plane GN ----
__global__ __launch_bounds__(256) void k_sm(
    const float* __restrict__ Sp, const float* __restrict__ w1,
    const float* __restrict__ b1, const float* __restrict__ g1,
    const float* __restrict__ bb1, const float* __restrict__ w2,
    const float* __restrict__ b2, const float* __restrict__ g2,
    const float* __restrict__ bb2, float* __restrict__ accg) {
  __shared__ float p0[4096];
  __shared__ float p1[4096];
  __shared__ float red[8];
  int bk = blockIdx.x, b = bk >> 3, k = bk & 7;
  const float4* src = (const float4*)(Sp + (size_t)bk * 4096);
  float4* d0 = (float4*)p0;
  for (int i = threadIdx.x; i < 1024; i += 256) d0[i] = src[i];
  float W1[9], W2[9];
#pragma unroll
  for (int q = 0; q < 9; ++q) { W1[q] = w1[k * 9 + q]; W2[q] = w2[k * 9 + q]; }
  __syncthreads();
  int wid = threadIdx.x >> 6, lane = threadIdx.x & 63;
  float y[16];
  float s1 = 0.f, s2 = 0.f;
#pragma unroll
  for (int v = 0; v < 16; ++v) {
    int p = v * 256 + threadIdx.x;
    int i = p >> 6, j = p & 63;
    float a = b1[k];
#pragma unroll
    for (int dy = 0; dy < 3; ++dy) {
      int ii = i + dy - 1;
      if (ii < 0 || ii > 63) continue;
#pragma unroll
      for (int dx = 0; dx < 3; ++dx) {
        int jj = j + dx - 1;
        if (jj < 0 || jj > 63) continue;
        a = fmaf(W1[dy * 3 + dx], p0[(ii << 6) + jj], a);
      }
    }
    y[v] = a;
    s1 += a;
    s2 = fmaf(a, a, s2);
  }
  s1 = wred(s1); s2 = wred(s2);
  if (lane == 0) { red[wid * 2] = s1; red[wid * 2 + 1] = s2; }
  __syncthreads();
  float mean = (red[0] + red[2] + red[4] + red[6]) * (1.f / 4096.f);
  float var = (red[1] + red[3] + red[5] + red[7]) * (1.f / 4096.f) - mean * mean;
  float inv = rsqrtf(var + 1e-5f) * g1[k];
  float sh = bb1[k];
  __syncthreads();
#pragma unroll
  for (int v = 0; v < 16; ++v) {
    int p = v * 256 + threadIdx.x;
    p1[p] = fmaxf((y[v] - mean) * inv + sh, 0.f);
  }
  __syncthreads();
  s1 = 0.f; s2 = 0.f;
#pragma unroll
  for (int v = 0; v < 16; ++v) {
    int p = v * 256 + threadIdx.x;
    int i = p >> 6, j = p & 63;
    float a = b2[k];
#pragma unroll
    for (int dy = 0; dy < 3; ++dy) {
      int ii = i + dy - 1;
      if (ii < 0 || ii > 63) continue;
#pragma unroll
      for (int dx = 0; dx < 3; ++dx) {
        int jj = j + dx - 1;
        if (jj < 0 || jj > 63) continue;
        a = fmaf(W2[dy * 3 + dx], p1[(ii << 6) + jj], a);
      }
    }
    y[v] = a;
    s1 += a;
    s2 = fmaf(a, a, s2);
  }
  s1 = wred(s1); s2 = wred(s2);
  if (lane == 0) { red[wid * 2] = s1; red[wid * 2 + 1] = s2; }
  __syncthreads();
  float mean2 = (red[0] + red[2] + red[4] + red[6]) * (1.f / 4096.f);
  float var2 = (red[1] + red[3] + red[5] + red[7]) * (1.f / 4096.f) - mean2 * mean2;
  float inv2 = rsqrtf(var2 + 1e-5f) * g2[k];
  float sh2 = bb2[k];
  float sd = 0.f;
#pragma unroll
  for (int v = 0; v < 16; ++v) {
    int p = v * 256 + threadIdx.x;
    float sm = (y[v] - mean2) * inv2 + sh2;
    float dd = sm - p0[p];
    sd = fmaf(dd, dd, sd);
  }
  sd = wred(sd);
  __syncthreads();
  if (lane == 0) red[wid] = sd;
  __syncthreads();
  if (threadIdx.x == 0)
    atomicAdd(&accg[8 + b], (red[0] + red[1] + red[2] + red[3]) * (1.f / 32768.f));
}

// ---- edge conv via bf16 MFMA: block = image row, 64px x 32ch, K'=9*384 ----
__global__ __launch_bounds__(256) void k_ecconv(
    const short* __restrict__ fb, const short* __restrict__ wq,
    const float* __restrict__ bias1, float* __restrict__ eraw,
    float* __restrict__ accg) {
  __shared__ __align__(16) short Abuf[3 * 67 * 32];  // [r][px slot 0..66][32d]
  __shared__ __align__(16) short Wbuf[9 * 32 * 32];  // [q][o][32d]
  __shared__ float sW1[4][32], sW2[4][32];
  int blk = blockIdx.x;
  int b = blk >> 6, i = blk & 63;
  int tid = threadIdx.x;
  int wid = tid >> 6, lane = tid & 63;
  int m = lane & 15, kg = lane >> 4;
  if (tid < 36) {
    int zkg = tid & 3, sl = (tid >> 2) % 3, r = tid / 12;
    int slot = sl == 0 ? 0 : (sl == 1 ? 65 : 66);
    *(short8b*)&Abuf[(r * 67 + slot) * 32 + zkg * 8] = (short8b)0;
  }
  f32x4 acc0 = {0.f, 0.f, 0.f, 0.f};
  f32x4 acc1 = {0.f, 0.f, 0.f, 0.f};
  int abase = (wid * 16 + m) * 32 + kg * 8;
  int bbase = m * 32 + kg * 8;
  for (int c = 0; c < 12; ++c) {
    __syncthreads();
#pragma unroll
    for (int s = 0; s < 3; ++s) {
      int cid = tid + (s << 8);
      int akg = cid & 3, px = (cid >> 2) & 63, r = cid >> 8;
      int ii = i + r - 1;
      short8b v = (short8b)0;
      if (ii >= 0 && ii < 64)
        v = *(const short8b*)(fb +
              ((size_t)((b << 12) + (ii << 6) + px)) * D_ + c * 32 + akg * 8);
      *(short8b*)&Abuf[(r * 67 + px + 1) * 32 + akg * 8] = v;
    }
    for (int l = tid; l < 1152; l += 256) {
      int wkg = l & 3, oo = (l >> 2) & 31, q = l >> 7;
      short8b wv =
          *(const short8b*)(wq + ((size_t)(q * 32 + oo)) * D_ + c * 32 + wkg * 8);
      *(short8b*)&Wbuf[(q * 32 + oo) * 32 + wkg * 8] = wv;
    }
    __syncthreads();
#pragma unroll
    for (int q = 0; q < 9; ++q) {
      short8b av = *(const short8b*)&Abuf[abase + ((q / 3) * 67 + (q % 3)) * 32];
      short8b bv0 = *(const short8b*)&Wbuf[bbase + q * 1024];
      short8b bv1 = *(const short8b*)&Wbuf[bbase + q * 1024 + 512];
      acc0 = __builtin_amdgcn_mfma_f32_16x16x32_bf16(av, bv0, acc0, 0, 0, 0);
      acc1 = __builtin_amdgcn_mfma_f32_16x16x32_bf16(av, bv1, acc1, 0, 0, 0);
    }
  }
  int o0 = m, o1 = 16 + m;
  float bs0 = bias1[o0], bs1 = bias1[o1];
  float s1a = 0.f, s2a = 0.f, s1b = 0.f, s2b = 0.f;
  int jbase = wid * 16 + kg * 4;
#pragma unroll
  for (int rg = 0; rg < 4; ++rg) {
    float v0 = acc0[rg] + bs0;
    float v1 = acc1[rg] + bs1;
    int j = jbase + rg;
    size_t px = ((size_t)((b << 12) + (i << 6) + j)) * 32;
    eraw[px + o0] = v0;
    eraw[px + o1] = v1;
    s1a += v0; s2a = fmaf(v0, v0, s2a);
    s1b += v1; s2b = fmaf(v1, v1, s2b);
  }
  s1a += __shfl_xor(s1a, 16); s1a += __shfl_xor(s1a, 32);
  s2a += __shfl_xor(s2a, 16); s2a += __shfl_xor(s2a, 32);
  s1b += __shfl_xor(s1b, 16); s1b += __shfl_xor(s1b, 32);
  s2b += __shfl_xor(s2b, 16); s2b += __shfl_xor(s2b, 32);
  if (lane < 16) {
    sW1[wid][lane] = s1a; sW2[wid][lane] = s2a;
    sW1[wid][lane + 16] = s1b; sW2[wid][lane + 16] = s2b;
  }
  __syncthreads();
  if (tid < 32) {
    float t1 = sW1[0][tid] + sW1[1][tid] + sW1[2][tid] + sW1[3][tid];
    float t2 = sW2[0][tid] + sW2[1][tid] + sW2[2][tid] + sW2[3][tid];
    t1 += __shfl_xor(t1, 1); t1 += __shfl_xor(t1, 2);
    t2 += __shfl_xor(t2, 1); t2 += __shfl_xor(t2, 2);
    if ((tid & 3) == 0) {
      atomicAdd(&accg[16 + b * 16 + (tid >> 2) * 2], t1);
      atomicAdd(&accg[16 + b * 16 + (tid >> 2) * 2 + 1], t2);
    }
  }
}

// ---- GN + relu + 1x1 conv + sigmoid -> ew (B,T); eraw pixel-major [b][t][32]
__global__ __launch_bounds__(256) void k_ecfinal(
    const float* __restrict__ eraw, const float* __restrict__ accg,
    const float* __restrict__ gng, const float* __restrict__ gnb,
    const float* __restrict__ w2, const float* __restrict__ b2,
    float* __restrict__ ew) {
  __shared__ float st[16];
  int idx = blockIdx.x * 256 + threadIdx.x;
  int b = idx >> 12;
  if (threadIdx.x < 16) st[threadIdx.x] = accg[16 + b * 16 + threadIdx.x];
  __syncthreads();
  float a = b2[0];
  const float4* er = (const float4*)(eraw + (size_t)idx * 32);
#pragma unroll
  for (int oq = 0; oq < 8; ++oq) {
    float mean = st[oq * 2] * (1.f / 16384.f);
    float var = st[oq * 2 + 1] * (1.f / 16384.f) - mean * mean;
    float inv = rsqrtf(var + 1e-5f);
    float4 e = er[oq];
    int o = oq * 4;
    float v0 = (e.x - mean) * inv * gng[o + 0] + gnb[o + 0];
    float v1 = (e.y - mean) * inv * gng[o + 1] + gnb[o + 1];
    float v2 = (e.z - mean) * inv * gng[o + 2] + gnb[o + 2];
    float v3 = (e.w - mean) * inv * gng[o + 3] + gnb[o + 3];
    a = fmaf(fmaxf(v0, 0.f), w2[o + 0], a);
    a = fmaf(fmaxf(v1, 0.f), w2[o + 1], a);
    a = fmaf(fmaxf(v2, 0.f), w2[o + 2], a);
    a = fmaf(fmaxf(v3, 0.f), w2[o + 3], a);
  }
  ew[idx] = 1.f / (1.f + expf(-a));
}

// ---- feature-smoothness gradient sums (bf16 feat) ----
__global__ __launch_bounds__(256) void k_fsloss(const short* __restrict__ fb,
                                                const float* __restrict__ ew,
                                                float* __restrict__ accg) {
  float sy = 0.f, sx = 0.f;
  const int N = B_ * T_ * 48;
  for (int idx = blockIdx.x * 256 + threadIdx.x; idx < N; idx += gridDim.x * 256) {
    int d8 = idx % 48;
    int rt = idx / 48;
    int t = rt & (T_ - 1);
    int i = t >> 6, j = t & 63;
    const short8b* fp = (const short8b*)(fb + (size_t)rt * D_) + d8;
    short8b f0 = *fp;
    if (i < 63) {
      short8b f1 = fp[64 * 48];
      float w = ew[rt + 64];
      float a = 0.f;
#pragma unroll
      for (int u = 0; u < 8; ++u) {
        float d = bf2f(f1[u]) - bf2f(f0[u]);
        a = fmaf(d, d, a);
      }
      sy += w * a;
    }
    if (j < 63) {
      short8b f1 = fp[48];
      float w = ew[rt + 1];
      float a = 0.f;
#pragma unroll
      for (int u = 0; u < 8; ++u) {
        float d = bf2f(f1[u]) - bf2f(f0[u]);
        a = fmaf(d, d, a);
      }
      sx += w * a;
    }
  }
  sy = wred(sy);
  sx = wred(sx);
  __shared__ float lds[8];
  int wid = threadIdx.x >> 6, lane = threadIdx.x & 63;
  if (lane == 0) { lds[wid * 2] = sy; lds[wid * 2 + 1] = sx; }
  __syncthreads();
  if (threadIdx.x == 0) {
    atomicAdd(&accg[12], lds[0] + lds[2] + lds[4] + lds[6]);
    atomicAdd(&accg[13], lds[1] + lds[3] + lds[5] + lds[7]);
  }
}

// ---- final scalar assembly ----
__global__ void k_final(const float* __restrict__ accg, float* __restrict__ out) {
  if (threadIdx.x != 0 || blockIdx.x != 0) return;
  float total = 0.f;
  for (int b = 0; b < 4; ++b) {
    const float* SSb = accg + 80 + b * 64;
    float ssq = 0.f;
    for (int v = 0; v < 64; ++v) ssq += SSb[v] * SSb[v];
    float ssn = sqrtf(ssq);
    float tgt = 1.f / (sqrtf(8.f) + 1e-6f);
    float inv = 1.f / (ssn + 1e-6f);
    float lo = 0.f;
    for (int kk = 0; kk < 8; ++kk)
      for (int ll = 0; ll < 8; ++ll) {
        float dd = SSb[kk * 8 + ll] * inv - (kk == ll ? tgt : 0.f);
        lo += dd * dd;
      }
    lo = sqrtf(lo);
    float lc = -accg[b] / (accg[4 + b] + 1e-6f);
    total += lc + lo + 0.01f * accg[8 + b];
  }
  total *= 0.25f;
  const float cnt = 4.f * 384.f * 63.f * 64.f;
  float ly = accg[12] / cnt * (1.f / 384.f);
  float lx = accg[13] / cnt * (1.f / 384.f);
  out[131072] = total + 0.09f * 0.5f * (ly + lx);
}

extern "C" void kernel_launch(void* const* d_in, const int* in_sizes, int n_in,
                              void* d_out, int out_size, void* d_ws, size_t ws_size,
                              hipStream_t stream) {
  const float* feat = (const float*)d_in[0];
  const float* gcn_w0 = (const float*)d_in[1];
  const float* gcn_b0 = (const float*)d_in[2];
  const float* gcn_w = (const float*)d_in[3];
  const float* gcn_b = (const float*)d_in[4];
  const float* ln_g = (const float*)d_in[5];
  const float* ln_b = (const float*)d_in[6];
  const float* res_w = (const float*)d_in[7];
  const float* res_b = (const float*)d_in[8];
  const float* res_ln_g = (const float*)d_in[9];
  const float* res_ln_b = (const float*)d_in[10];
  const float* mlp_w1 = (const float*)d_in[11];
  const float* mlp_b1 = (const float*)d_in[12];
  const float* mlp_ln_g = (const float*)d_in[13];
  const float* mlp_ln_b = (const float*)d_in[14];
  const float* mlp_w2 = (const float*)d_in[15];
  const float* mlp_b2 = (const float*)d_in[16];
  const float* sm_w1 = (const float*)d_in[17];
  const float* sm_b1 = (const float*)d_in[18];
  const float* sm_g1 = (const float*)d_in[19];
  const float* sm_bb1 = (const float*)d_in[20];
  const float* sm_w2 = (const float*)d_in[21];
  const float* sm_b2 = (const float*)d_in[22];
  const float* sm_g2 = (const float*)d_in[23];
  const float* sm_bb2 = (const float*)d_in[24];
  const float* ec_w1 = (const float*)d_in[25];
  const float* ec_b1 = (const float*)d_in[26];
  const float* ec_gn_g = (const float*)d_in[27];
  const float* ec_gn_b = (const float*)d_in[28];
  const float* ec_w2 = (const float*)d_in[29];
  const float* ec_b2 = (const float*)d_in[30];

  float* out = (float*)d_out;
  float* ws = (float*)d_ws;
  float* acc = ws;                       // 512 floats
  float* xw = ws + 512;                  // B*T*64
  float* xbuf = xw + 1048576;            // B*T*64
  float* resbuf = xbuf + 1048576;        // B*T*64
  float* Sp = resbuf + 1048576;          // B*K*T
  float* eraw = Sp + 131072;             // B*T*32 (pixel-major)
  float* ew = eraw + 524288;             // B*T
  short* wqb = (short*)(ew + 16384);     // 110592 shorts (bf16)
  short* wb = wqb + 110592;              // 49152 shorts (bf16, frag order)
  short* fb = wb + 49152;                // B*T*384 shorts (bf16 feat)
  float* S = out;                        // (B,T,K) straight into d_out

  k_featbf<<<3072, 256, 0, stream>>>(feat, fb);
  k_wq<<<432, 256, 0, stream>>>(ec_w1, wqb, acc);
  k_wb<<<24, 256, 0, stream>>>(gcn_w0, res_w, wb);

  k_gemm0<<<256, 256, 0, stream>>>(fb, wb, gcn_w0, res_w, res_b, res_ln_g,
                                   res_ln_b, xw, resbuf);
  k_stencil<<<B_ * T_ / 4, 256, 0, stream>>>(xw, gcn_b0, ln_g, ln_b, resbuf, xbuf);
  for (int i = 1; i < 4; ++i) {
    k_gemm64<<<B_ * T_ / 32, 256, 0, stream>>>(xbuf, gcn_w + (i - 1) * 4096, xw);
    k_stencil<<<B_ * T_ / 4, 256, 0, stream>>>(xw, gcn_b + (i - 1) * 64,
                                               ln_g + i * 64, ln_b + i * 64, xbuf,
                                               xbuf);
  }
  k_mlp<<<B_ * T_ / 4, 256, 0, stream>>>(xbuf, mlp_w1, mlp_b1, mlp_ln_g, mlp_ln_b,
                                         mlp_w2, mlp_b2, S, Sp);

  k_cutss<<<B_ * T_ / 32, 256, 0, stream>>>(S, acc);
  k_sm<<<32, 256, 0, stream>>>(Sp, sm_w1, sm_b1, sm_g1, sm_bb1, sm_w2, sm_b2, sm_g2,
                               sm_bb2, acc);

  k_ecconv<<<256, 256, 0, stream>>>(fb, wqb, ec_b1, eraw, acc);
  k_ecfinal<<<B_ * T_ / 256, 256, 0, stream>>>(eraw, acc, ec_gn_g, ec_gn_b, ec_w2,
                                               ec_b2, ew);
  k_fsloss<<<2048, 256, 0, stream>>>(fb, ew, acc);
  k_final<<<1, 64, 0, stream>>>(acc, out);
}

// Round 6
// 227.351 us; speedup vs baseline: 1.6364x; 1.2073x over previous
//
#include <hip/hip_runtime.h>
#include <hip/hip_bf16.h>

// ---------------------------------------------------------------------------
// DeepCut fused pipeline. B=4, T=4096 (64x64), D=384, K=8, CH=64, NL=4.
// Graph = 5x5 box stencil with separable D^-1/2 normalization u(i)*u(j).
// gemm0 + edge-conv use bf16 MFMA; LN/softmax/losses stay fp32.
// Accumulator map (512 floats, all zeroed by k_wq):
//  [0..15]   cut num, b*4 + (blk&3)     [16..31] cut den
//  [32..63]  fs partials, (blk&15)*2 (sy), +1 (sx)
//  [64..127] ec GN stats, 64 + b*16 + i
//  [128..383] SS, 128 + b*64 + idx
//  [384..391] sm loss, 384 + b*2 + (blk&1)
// ---------------------------------------------------------------------------

#define B_ 4
#define T_ 4096
#define D_ 384
#define K_ 8
#define CH_ 64

typedef __attribute__((ext_vector_type(8))) short short8b;
typedef __attribute__((ext_vector_type(4))) float f32x4;

__device__ __forceinline__ float wred(float v) {
#pragma unroll
  for (int off = 32; off > 0; off >>= 1) v += __shfl_xor(v, off);
  return v;
}

__device__ __forceinline__ short bf16rne(float f) {
  unsigned u = __float_as_uint(f);
  unsigned r = (u + 0x7FFFu + ((u >> 16) & 1u)) >> 16;
  return (short)r;
}

__device__ __forceinline__ float bf2f(short s) {
  return __uint_as_float(((unsigned)(unsigned short)s) << 16);
}

// u(i) = rsqrt(#valid offsets in [-2,2] along one axis)
__device__ __forceinline__ float uval(int i) {
  int c = (i < 2 ? i : 2) + ((63 - i) < 2 ? (63 - i) : 2) + 1;
  return rsqrtf((float)c);
}

// ---- feat fp32 -> bf16 (B*T*384) ----
__global__ __launch_bounds__(256) void k_featbf(const float* __restrict__ feat,
                                                short* __restrict__ fb) {
  int tid = blockIdx.x * 256 + threadIdx.x;  // one per 8 elems; grid 3072
  const float4* s = (const float4*)feat + (size_t)tid * 2;
  float4 a = s[0], b = s[1];
  short8b v;
  v[0] = bf16rne(a.x); v[1] = bf16rne(a.y); v[2] = bf16rne(a.z); v[3] = bf16rne(a.w);
  v[4] = bf16rne(b.x); v[5] = bf16rne(b.y); v[6] = bf16rne(b.z); v[7] = bf16rne(b.w);
  *(short8b*)(fb + (size_t)tid * 8) = v;
}

// ---- transpose ec_w1 (32,384,3,3) -> wq[q][o][d] bf16; zero acc ----
__global__ void k_wq(const float* __restrict__ w, short* __restrict__ wq,
                     float* __restrict__ accg) {
  if (blockIdx.x == 0) {
    accg[threadIdx.x] = 0.f;
    accg[threadIdx.x + 256] = 0.f;
  }
  int idx = blockIdx.x * 256 + threadIdx.x;
  if (idx >= 32 * 384 * 9) return;
  int q = idx % 9;
  int rest = idx / 9;
  int d = rest % 384;
  int o = rest / 384;
  wq[((size_t)(q * 32 + o)) * 384 + d] = bf16rne(w[idx]);
}

// ---- B = [w0 | resw] (384 x 128) -> MFMA-fragment-ordered bf16 ----
__global__ void k_wb(const float* __restrict__ w0, const float* __restrict__ resw,
                     short* __restrict__ wb) {
  int u = blockIdx.x * 256 + threadIdx.x;  // 0..6143
  int l = u & 63, f = (u >> 6) & 7, s = u >> 9;
  int c = f * 16 + (l & 15);
  int k0 = s * 32 + ((l >> 4) << 3);
  const float* src = (c < 64) ? (w0 + c) : (resw + (c - 64));
  short8b v;
#pragma unroll
  for (int j = 0; j < 8; ++j) v[j] = bf16rne(src[(size_t)(k0 + j) * 64]);
  *(short8b*)(wb + (size_t)u * 8) = v;
}

// ---- layer-0 GEMM via bf16 MFMA: block = 64 rows x 128 cols (w0|resw), K=384
__global__ __launch_bounds__(256) void k_gemm0(
    const short* __restrict__ fb, const short* __restrict__ wb,
    const float* __restrict__ w0, const float* __restrict__ resw,
    const float* __restrict__ resb, const float* __restrict__ resg,
    const float* __restrict__ reslb, float* __restrict__ xw,
    float* __restrict__ res) {
  __shared__ __align__(16) short Ab[24576];  // 48KB, fragment-ordered
  __shared__ __align__(16) short Bb[49152];  // 96KB, fragment-ordered
  int tid = threadIdx.x;
  int row0 = blockIdx.x * 64;
  const short8b* wb8 = (const short8b*)wb;
  short8b* Bb8 = (short8b*)Bb;
#pragma unroll
  for (int it = 0; it < 24; ++it) Bb8[tid + it * 256] = wb8[tid + it * 256];
  short8b* Ab8 = (short8b*)Ab;
#pragma unroll
  for (int it = 0; it < 12; ++it) {
    int u = it * 256 + tid;
    int l = u & 63, w = (u >> 6) & 3, s = u >> 8;
    int row = w * 16 + (l & 15);
    int k = s * 32 + ((l >> 4) << 3);
    Ab8[u] = *(const short8b*)(fb + (size_t)(row0 + row) * 384 + k);
  }
  __syncthreads();
  int wid = tid >> 6, lane = tid & 63;
  f32x4 acc[8];
#pragma unroll
  for (int f = 0; f < 8; ++f) acc[f] = (f32x4){0.f, 0.f, 0.f, 0.f};
#pragma unroll
  for (int s = 0; s < 12; ++s) {
    short8b av = Ab8[(s * 4 + wid) * 64 + lane];
#pragma unroll
    for (int f = 0; f < 8; ++f) {
      short8b bv = Bb8[(s * 8 + f) * 64 + lane];
      acc[f] = __builtin_amdgcn_mfma_f32_16x16x32_bf16(av, bv, acc[f], 0, 0, 0);
    }
  }
  int g = lane >> 4, ln = lane & 15;
  float pw1[4], pw2[4], rw1[4], rw2[4], rb[4], rgam[4], rbet[4];
#pragma unroll
  for (int f = 0; f < 4; ++f) {
    int c = f * 16 + ln;
    pw1[f] = w0[384 * 64 + c];  pw2[f] = w0[385 * 64 + c];
    rw1[f] = resw[384 * 64 + c]; rw2[f] = resw[385 * 64 + c];
    rb[f] = resb[c]; rgam[f] = resg[c]; rbet[f] = reslb[c];
  }
#pragma unroll
  for (int r = 0; r < 4; ++r) {
    int grow = row0 + wid * 16 + g * 4 + r;
    int t = grow & (T_ - 1);
    float px = (float)(t & 63) * (1.f / 63.f);
    float py = (float)(t >> 6) * (1.f / 63.f);
    float rv[4];
    float s1 = 0.f, s2 = 0.f;
#pragma unroll
    for (int f = 0; f < 4; ++f) {
      float xv = acc[f][r] + px * pw1[f] + py * pw2[f];
      xw[(size_t)grow * 64 + f * 16 + ln] = xv;
      float v = acc[4 + f][r] + px * rw1[f] + py * rw2[f] + rb[f];
      rv[f] = v;
      s1 += v;
      s2 = fmaf(v, v, s2);
    }
#pragma unroll
    for (int off = 1; off < 16; off <<= 1) {
      s1 += __shfl_xor(s1, off);
      s2 += __shfl_xor(s2, off);
    }
    float mean = s1 * (1.f / 64.f);
    float var = s2 * (1.f / 64.f) - mean * mean;
    float inv = rsqrtf(var + 1e-5f);
#pragma unroll
    for (int f = 0; f < 4; ++f)
      res[(size_t)grow * 64 + f * 16 + ln] = (rv[f] - mean) * inv * rgam[f] + rbet[f];
  }
}

// ---- 64->64 GEMM, register-tiled: 32 rows/block, thread = 8 rows x 1 col ----
__global__ __launch_bounds__(256) void k_gemm64(const float* __restrict__ X,
                                                const float* __restrict__ W,
                                                float* __restrict__ Y) {
  __shared__ float sf[32 * 64];   // 8KB
  __shared__ float sW[64 * 64];   // 16KB
  int tid = threadIdx.x;
  size_t base = (size_t)blockIdx.x * 2048;
  const float4* x4 = (const float4*)(X + base);
  float4* sf4 = (float4*)sf;
#pragma unroll
  for (int l = 0; l < 2; ++l) sf4[tid + l * 256] = x4[tid + l * 256];
  const float4* w4 = (const float4*)W;
  float4* sW4 = (float4*)sW;
#pragma unroll
  for (int l = 0; l < 4; ++l) sW4[tid + l * 256] = w4[tid + l * 256];
  __syncthreads();
  int c = tid & 63, rg = tid >> 6;
  float a[8];
#pragma unroll
  for (int m = 0; m < 8; ++m) a[m] = 0.f;
  const float4* sfb = (const float4*)(sf + rg * 8 * 64);
#pragma unroll
  for (int kq = 0; kq < 16; ++kq) {
    float4 fv[8];
#pragma unroll
    for (int m = 0; m < 8; ++m) fv[m] = sfb[m * 16 + kq];
#pragma unroll
    for (int dk = 0; dk < 4; ++dk) {
      float wv = sW[(kq * 4 + dk) * 64 + c];
#pragma unroll
      for (int m = 0; m < 8; ++m)
        a[m] = fmaf(((const float*)&fv[m])[dk], wv, a[m]);
    }
  }
#pragma unroll
  for (int m = 0; m < 8; ++m)
    Y[base + (size_t)(rg * 8 + m) * 64 + c] = a[m];
}

// ---- stencil + bias + LN + ELU + residual ----
__global__ __launch_bounds__(256) void k_stencil(
    const float* __restrict__ xw, const float* __restrict__ bias,
    const float* __restrict__ lng, const float* __restrict__ lnb,
    const float* __restrict__ resid, float* __restrict__ xout) {
  int r = threadIdx.x >> 6, c = threadIdx.x & 63;
  int row = blockIdx.x * 4 + r;
  int b = row >> 12, t = row & (T_ - 1);
  int i = t >> 6, j = t & 63;
  float ui = uval(i), uj = uval(j);
  float s = 0.f;
#pragma unroll
  for (int di = -2; di <= 2; ++di) {
    int ii = i + di;
    if (ii < 0 || ii > 63) continue;
    float wi = uval(ii);
#pragma unroll
    for (int dj = -2; dj <= 2; ++dj) {
      int jj = j + dj;
      if (jj < 0 || jj > 63) continue;
      s = fmaf(wi * uval(jj), xw[((size_t)((b << 12) + (ii << 6) + jj)) * 64 + c], s);
    }
  }
  float h = ui * uj * s + bias[c];
  float m = wred(h) * (1.f / 64.f);
  float d = h - m;
  float v = wred(d * d) * (1.f / 64.f);
  float n = d * rsqrtf(v + 1e-5f) * lng[c] + lnb[c];
  float e = n > 0.f ? n : (expf(n) - 1.f);
  xout[(size_t)row * 64 + c] = e + resid[(size_t)row * 64 + c];
}

// ---- MLP head: h1 = elu(LN(x@w1+b1)); S = softmax(h1@w2+b2); also writes Sp ----
__global__ __launch_bounds__(256) void k_mlp(
    const float* __restrict__ X, const float* __restrict__ w1,
    const float* __restrict__ b1, const float* __restrict__ lng,
    const float* __restrict__ lnb, const float* __restrict__ w2,
    const float* __restrict__ b2, float* __restrict__ S, float* __restrict__ Sp) {
  int r = threadIdx.x >> 6, lane = threadIdx.x & 63;
  size_t row = (size_t)blockIdx.x * 4 + r;
  float xv = X[row * 64 + lane];
  float a = b1[lane];
#pragma unroll
  for (int k = 0; k < 64; ++k) {
    float xk = __shfl(xv, k);
    a = fmaf(xk, w1[k * 64 + lane], a);
  }
  float m = wred(a) * (1.f / 64.f);
  float d = a - m;
  float v = wred(d * d) * (1.f / 64.f);
  float h = d * rsqrtf(v + 1e-5f) * lng[lane] + lnb[lane];
  h = h > 0.f ? h : (expf(h) - 1.f);
  float lg0 = wred(h * w2[lane * 8 + 0]) + b2[0];
  float lg1 = wred(h * w2[lane * 8 + 1]) + b2[1];
  float lg2 = wred(h * w2[lane * 8 + 2]) + b2[2];
  float lg3 = wred(h * w2[lane * 8 + 3]) + b2[3];
  float lg4 = wred(h * w2[lane * 8 + 4]) + b2[4];
  float lg5 = wred(h * w2[lane * 8 + 5]) + b2[5];
  float lg6 = wred(h * w2[lane * 8 + 6]) + b2[6];
  float lg7 = wred(h * w2[lane * 8 + 7]) + b2[7];
  float mx = fmaxf(fmaxf(fmaxf(lg0, lg1), fmaxf(lg2, lg3)),
                   fmaxf(fmaxf(lg4, lg5), fmaxf(lg6, lg7)));
  lg0 = expf(lg0 - mx); lg1 = expf(lg1 - mx); lg2 = expf(lg2 - mx);
  lg3 = expf(lg3 - mx); lg4 = expf(lg4 - mx); lg5 = expf(lg5 - mx);
  lg6 = expf(lg6 - mx); lg7 = expf(lg7 - mx);
  float inv = 1.f / (lg0 + lg1 + lg2 + lg3 + lg4 + lg5 + lg6 + lg7);
  if (lane < 8) {
    float val = lane == 0 ? lg0 : lane == 1 ? lg1 : lane == 2 ? lg2 :
                lane == 3 ? lg3 : lane == 4 ? lg4 : lane == 5 ? lg5 :
                lane == 6 ? lg6 : lg7;
    val *= inv;
    int b = (int)(row >> 12), t = (int)(row & (T_ - 1));
    S[row * 8 + lane] = val;
    Sp[((size_t)((b << 3) + lane) << 12) + t] = val;
  }
}

// ---- merged normalized-cut (all blocks) + SS (blocks 0..31) ----
__global__ __launch_bounds__(256) void k_cutss(const float* __restrict__ S,
                                               float* __restrict__ accg) {
  {
    int k = threadIdx.x & 7;
    int tl = threadIdx.x >> 3;
    int gid = blockIdx.x * 32 + tl;
    int b = gid >> 12, t = gid & (T_ - 1);
    int i = t >> 6, j = t & 63;
    float ui = uval(i), uj = uval(j);
    float as = 0.f, sui = 0.f, suj = 0.f;
#pragma unroll
    for (int di = -2; di <= 2; ++di) {
      int ii = i + di;
      if (ii < 0 || ii > 63) continue;
      float wi = uval(ii);
      sui += wi;
#pragma unroll
      for (int dj = -2; dj <= 2; ++dj) {
        int jj = j + dj;
        if (jj < 0 || jj > 63) continue;
        as = fmaf(wi * uval(jj),
                  S[((size_t)((b << 12) + (ii << 6) + jj)) * 8 + k], as);
      }
    }
#pragma unroll
    for (int dj = -2; dj <= 2; ++dj) {
      int jj = j + dj;
      if (jj >= 0 && jj <= 63) suj += uval(jj);
    }
    as *= ui * uj;
    float sv = S[(size_t)gid * 8 + k];
    float degA = ui * uj * sui * suj;
    float numv = wred(sv * as);
    float denv = wred(sv * sv * degA);
    __shared__ float lds[8];
    int wid = threadIdx.x >> 6, lane = threadIdx.x & 63;
    if (lane == 0) { lds[wid * 2] = numv; lds[wid * 2 + 1] = denv; }
    __syncthreads();
    if (threadIdx.x == 0) {
      int slot = b * 4 + (blockIdx.x & 3);
      atomicAdd(&accg[slot], lds[0] + lds[2] + lds[4] + lds[6]);
      atomicAdd(&accg[16 + slot], lds[1] + lds[3] + lds[5] + lds[7]);
    }
  }
  if (blockIdx.x < 32) {
    int b = blockIdx.x >> 3, chunk = blockIdx.x & 7;
    int wid = threadIdx.x >> 6, lane = threadIdx.x & 63;
    int kk = lane >> 3, ll = lane & 7;
    int t0 = chunk * 512 + wid * 128;
    float a = 0.f;
    const float* Sb = S + ((size_t)b << 12) * 8;
    for (int it = 0; it < 128; ++it) {
      const float* sr = Sb + (size_t)(t0 + it) * 8;
      a = fmaf(sr[kk], sr[ll], a);
    }
    __shared__ float lds2[256];
    lds2[threadIdx.x] = a;
    __syncthreads();
    if (threadIdx.x < 64) {
      float s = lds2[threadIdx.x] + lds2[threadIdx.x + 64] +
                lds2[threadIdx.x + 128] + lds2[threadIdx.x + 192];
      atomicAdd(&accg[128 + b * 64 + threadIdx.x], s);
    }
  }
}

// ---- spatial smoothness: per (b,k) plane, 2x depthwise conv3x3 + per-plane GN ----
__global__ __launch_bounds__(256) void k_sm(
    const float* __restrict__ Sp, const float* __restrict__ w1,
    const float* __restrict__ b1, const float* __restrict__ g1,
    const float* __restrict__ bb1, const float* __restrict__ w2,
    const float* __restrict__ b2, const float* __restrict__ g2,
    const float* __restrict__ bb2, float* __restrict__ accg) {
  __shared__ float p0[4096];
  __shared__ float p1[4096];
  __shared__ float red[8];
  int bk = blockIdx.x, b = bk >> 3, k = bk & 7;
  const float4* src = (const float4*)(Sp + (size_t)bk * 4096);
  float4* d0 = (float4*)p0;
  for (int i = threadIdx.x; i < 1024; i += 256) d0[i] = src[i];
  float W1[9], W2[9];
#pragma unroll
  for (int q = 0; q < 9; ++q) { W1[q] = w1[k * 9 + q]; W2[q] = w2[k * 9 + q]; }
  __syncthreads();
  int wid = threadIdx.x >> 6, lane = threadIdx.x & 63;
  float y[16];
  float s1 = 0.f, s2 = 0.f;
#pragma unroll
  for (int v = 0; v < 16; ++v) {
    int p = v * 256 + threadIdx.x;
    int i = p >> 6, j = p & 63;
    float a = b1[k];
#pragma unroll
    for (int dy = 0; dy < 3; ++dy) {
      int ii = i + dy - 1;
      if (ii < 0 || ii > 63) continue;
#pragma unroll
      for (int dx = 0; dx < 3; ++dx) {
        int jj = j + dx - 1;
        if (jj < 0 || jj > 63) continue;
        a = fmaf(W1[dy * 3 + dx], p0[(ii << 6) + jj], a);
      }
    }
    y[v] = a;
    s1 += a;
    s2 = fmaf(a, a, s2);
  }
  s1 = wred(s1); s2 = wred(s2);
  if (lane == 0) { red[wid * 2] = s1; red[wid * 2 + 1] = s2; }
  __syncthreads();
  float mean = (red[0] + red[2] + red[4] + red[6]) * (1.f / 4096.f);
  float var = (red[1] + red[3] + red[5] + red[7]) * (1.f / 4096.f) - mean * mean;
  float inv = rsqrtf(var + 1e-5f) * g1[k];
  float sh = bb1[k];
  __syncthreads();
#pragma unroll
  for (int v = 0; v < 16; ++v) {
    int p = v * 256 + threadIdx.x;
    p1[p] = fmaxf((y[v] - mean) * inv + sh, 0.f);
  }
  __syncthreads();
  s1 = 0.f; s2 = 0.f;
#pragma unroll
  for (int v = 0; v < 16; ++v) {
    int p = v * 256 + threadIdx.x;
    int i = p >> 6, j = p & 63;
    float a = b2[k];
#pragma unroll
    for (int dy = 0; dy < 3; ++dy) {
      int ii = i + dy - 1;
      if (ii < 0 || ii > 63) continue;
#pragma unroll
      for (int dx = 0; dx < 3; ++dx) {
        int jj = j + dx - 1;
        if (jj < 0 || jj > 63) continue;
        a = fmaf(W2[dy * 3 + dx], p1[(ii << 6) + jj], a);
      }
    }
    y[v] = a;
    s1 += a;
    s2 = fmaf(a, a, s2);
  }
  s1 = wred(s1); s2 = wred(s2);
  if (lane == 0) { red[wid * 2] = s1; red[wid * 2 + 1] = s2; }
  __syncthreads();
  float mean2 = (red[0] + red[2] + red[4] + red[6]) * (1.f / 4096.f);
  float var2 = (red[1] + red[3] + red[5] + red[7]) * (1.f / 4096.f) - mean2 * mean2;
  float inv2 = rsqrtf(var2 + 1e-5f) * g2[k];
  float sh2 = bb2[k];
  float sd = 0.f;
#pragma unroll
  for (int v = 0; v < 16; ++v) {
    int p = v * 256 + threadIdx.x;
    float sm = (y[v] - mean2) * inv2 + sh2;
    float dd = sm - p0[p];
    sd = fmaf(dd, dd, sd);
  }
  sd = wred(sd);
  __syncthreads();
  if (lane == 0) red[wid] = sd;
  __syncthreads();
  if (threadIdx.x == 0)
    atomicAdd(&accg[384 + b * 2 + (blockIdx.x & 1)],
              (red[0] + red[1] + red[2] + red[3]) * (1.f / 32768.f));
}

// ---- edge conv via bf16 MFMA: block = image row, 64px x 32ch, K'=9*384 ----
__global__ __launch_bounds__(256) void k_ecconv(
    const short* __restrict__ fb, const short* __restrict__ wq,
    const float* __restrict__ bias1, float* __restrict__ eraw,
    float* __restrict__ accg) {
  __shared__ __align__(16) short Abuf[3 * 67 * 32];  // [r][px slot 0..66][32d]
  __shared__ __align__(16) short Wbuf[9 * 32 * 32];  // [q][o][32d]
  __shared__ float sW1[4][32], sW2[4][32];
  int blk = blockIdx.x;
  int b = blk >> 6, i = blk & 63;
  int tid = threadIdx.x;
  int wid = tid >> 6, lane = tid & 63;
  int m = lane & 15, kg = lane >> 4;
  if (tid < 36) {
    int zkg = tid & 3, sl = (tid >> 2) % 3, r = tid / 12;
    int slot = sl == 0 ? 0 : (sl == 1 ? 65 : 66);
    *(short8b*)&Abuf[(r * 67 + slot) * 32 + zkg * 8] = (short8b)0;
  }
  f32x4 acc0 = {0.f, 0.f, 0.f, 0.f};
  f32x4 acc1 = {0.f, 0.f, 0.f, 0.f};
  int abase = (wid * 16 + m) * 32 + kg * 8;
  int bbase = m * 32 + kg * 8;
  for (int c = 0; c < 12; ++c) {
    __syncthreads();
#pragma unroll
    for (int s = 0; s < 3; ++s) {
      int cid = tid + (s << 8);
      int akg = cid & 3, px = (cid >> 2) & 63, r = cid >> 8;
      int ii = i + r - 1;
      short8b v = (short8b)0;
      if (ii >= 0 && ii < 64)
        v = *(const short8b*)(fb +
              ((size_t)((b << 12) + (ii << 6) + px)) * D_ + c * 32 + akg * 8);
      *(short8b*)&Abuf[(r * 67 + px + 1) * 32 + akg * 8] = v;
    }
    for (int l = tid; l < 1152; l += 256) {
      int wkg = l & 3, oo = (l >> 2) & 31, q = l >> 7;
      short8b wv =
          *(const short8b*)(wq + ((size_t)(q * 32 + oo)) * D_ + c * 32 + wkg * 8);
      *(short8b*)&Wbuf[(q * 32 + oo) * 32 + wkg * 8] = wv;
    }
    __syncthreads();
#pragma unroll
    for (int q = 0; q < 9; ++q) {
      short8b av = *(const short8b*)&Abuf[abase + ((q / 3) * 67 + (q % 3)) * 32];
      short8b bv0 = *(const short8b*)&Wbuf[bbase + q * 1024];
      short8b bv1 = *(const short8b*)&Wbuf[bbase + q * 1024 + 512];
      acc0 = __builtin_amdgcn_mfma_f32_16x16x32_bf16(av, bv0, acc0, 0, 0, 0);
      acc1 = __builtin_amdgcn_mfma_f32_16x16x32_bf16(av, bv1, acc1, 0, 0, 0);
    }
  }
  int o0 = m, o1 = 16 + m;
  float bs0 = bias1[o0], bs1 = bias1[o1];
  float s1a = 0.f, s2a = 0.f, s1b = 0.f, s2b = 0.f;
  int jbase = wid * 16 + kg * 4;
#pragma unroll
  for (int rg = 0; rg < 4; ++rg) {
    float v0 = acc0[rg] + bs0;
    float v1 = acc1[rg] + bs1;
    int j = jbase + rg;
    size_t px = ((size_t)((b << 12) + (i << 6) + j)) * 32;
    eraw[px + o0] = v0;
    eraw[px + o1] = v1;
    s1a += v0; s2a = fmaf(v0, v0, s2a);
    s1b += v1; s2b = fmaf(v1, v1, s2b);
  }
  s1a += __shfl_xor(s1a, 16); s1a += __shfl_xor(s1a, 32);
  s2a += __shfl_xor(s2a, 16); s2a += __shfl_xor(s2a, 32);
  s1b += __shfl_xor(s1b, 16); s1b += __shfl_xor(s1b, 32);
  s2b += __shfl_xor(s2b, 16); s2b += __shfl_xor(s2b, 32);
  if (lane < 16) {
    sW1[wid][lane] = s1a; sW2[wid][lane] = s2a;
    sW1[wid][lane + 16] = s1b; sW2[wid][lane + 16] = s2b;
  }
  __syncthreads();
  if (tid < 32) {
    float t1 = sW1[0][tid] + sW1[1][tid] + sW1[2][tid] + sW1[3][tid];
    float t2 = sW2[0][tid] + sW2[1][tid] + sW2[2][tid] + sW2[3][tid];
    t1 += __shfl_xor(t1, 1); t1 += __shfl_xor(t1, 2);
    t2 += __shfl_xor(t2, 1); t2 += __shfl_xor(t2, 2);
    if ((tid & 3) == 0) {
      atomicAdd(&accg[64 + b * 16 + (tid >> 2) * 2], t1);
      atomicAdd(&accg[64 + b * 16 + (tid >> 2) * 2 + 1], t2);
    }
  }
}

// ---- GN + relu + 1x1 conv + sigmoid -> ew (B,T); eraw pixel-major [b][t][32]
__global__ __launch_bounds__(256) void k_ecfinal(
    const float* __restrict__ eraw, const float* __restrict__ accg,
    const float* __restrict__ gng, const float* __restrict__ gnb,
    const float* __restrict__ w2, const float* __restrict__ b2,
    float* __restrict__ ew) {
  __shared__ float st[16];
  int idx = blockIdx.x * 256 + threadIdx.x;
  int b = idx >> 12;
  if (threadIdx.x < 16) st[threadIdx.x] = accg[64 + b * 16 + threadIdx.x];
  __syncthreads();
  float a = b2[0];
  const float4* er = (const float4*)(eraw + (size_t)idx * 32);
#pragma unroll
  for (int oq = 0; oq < 8; ++oq) {
    float mean = st[oq * 2] * (1.f / 16384.f);
    float var = st[oq * 2 + 1] * (1.f / 16384.f) - mean * mean;
    float inv = rsqrtf(var + 1e-5f);
    float4 e = er[oq];
    int o = oq * 4;
    float v0 = (e.x - mean) * inv * gng[o + 0] + gnb[o + 0];
    float v1 = (e.y - mean) * inv * gng[o + 1] + gnb[o + 1];
    float v2 = (e.z - mean) * inv * gng[o + 2] + gnb[o + 2];
    float v3 = (e.w - mean) * inv * gng[o + 3] + gnb[o + 3];
    a = fmaf(fmaxf(v0, 0.f), w2[o + 0], a);
    a = fmaf(fmaxf(v1, 0.f), w2[o + 1], a);
    a = fmaf(fmaxf(v2, 0.f), w2[o + 2], a);
    a = fmaf(fmaxf(v3, 0.f), w2[o + 3], a);
  }
  ew[idx] = 1.f / (1.f + expf(-a));
}

// ---- feature-smoothness gradient sums (bf16 feat); scattered atomics ----
__global__ __launch_bounds__(256) void k_fsloss(const short* __restrict__ fb,
                                                const float* __restrict__ ew,
                                                float* __restrict__ accg) {
  float sy = 0.f, sx = 0.f;
  const int N = B_ * T_ * 48;
  for (int idx = blockIdx.x * 256 + threadIdx.x; idx < N; idx += gridDim.x * 256) {
    int d8 = idx % 48;
    int rt = idx / 48;
    int t = rt & (T_ - 1);
    int i = t >> 6, j = t & 63;
    const short8b* fp = (const short8b*)(fb + (size_t)rt * D_) + d8;
    short8b f0 = *fp;
    if (i < 63) {
      short8b f1 = fp[64 * 48];
      float w = ew[rt + 64];
      float a = 0.f;
#pragma unroll
      for (int u = 0; u < 8; ++u) {
        float d = bf2f(f1[u]) - bf2f(f0[u]);
        a = fmaf(d, d, a);
      }
      sy += w * a;
    }
    if (j < 63) {
      short8b f1 = fp[48];
      float w = ew[rt + 1];
      float a = 0.f;
#pragma unroll
      for (int u = 0; u < 8; ++u) {
        float d = bf2f(f1[u]) - bf2f(f0[u]);
        a = fmaf(d, d, a);
      }
      sx += w * a;
    }
  }
  sy = wred(sy);
  sx = wred(sx);
  __shared__ float lds[8];
  int wid = threadIdx.x >> 6, lane = threadIdx.x & 63;
  if (lane == 0) { lds[wid * 2] = sy; lds[wid * 2 + 1] = sx; }
  __syncthreads();
  if (threadIdx.x == 0) {
    int slot = 32 + (blockIdx.x & 15) * 2;
    atomicAdd(&accg[slot], lds[0] + lds[2] + lds[4] + lds[6]);
    atomicAdd(&accg[slot + 1], lds[1] + lds[3] + lds[5] + lds[7]);
  }
}

// ---- final scalar assembly ----
__global__ void k_final(const float* __restrict__ accg, float* __restrict__ out) {
  if (threadIdx.x != 0 || blockIdx.x != 0) return;
  float total = 0.f;
  for (int b = 0; b < 4; ++b) {
    const float* SSb = accg + 128 + b * 64;
    float ssq = 0.f;
    for (int v = 0; v < 64; ++v) ssq += SSb[v] * SSb[v];
    float ssn = sqrtf(ssq);
    float tgt = 1.f / (sqrtf(8.f) + 1e-6f);
    float inv = 1.f / (ssn + 1e-6f);
    float lo = 0.f;
    for (int kk = 0; kk < 8; ++kk)
      for (int ll = 0; ll < 8; ++ll) {
        float dd = SSb[kk * 8 + ll] * inv - (kk == ll ? tgt : 0.f);
        lo += dd * dd;
      }
    lo = sqrtf(lo);
    float num = accg[b * 4] + accg[b * 4 + 1] + accg[b * 4 + 2] + accg[b * 4 + 3];
    float den = accg[16 + b * 4] + accg[16 + b * 4 + 1] + accg[16 + b * 4 + 2] +
                accg[16 + b * 4 + 3];
    float lc = -num / (den + 1e-6f);
    float smv = accg[384 + b * 2] + accg[385 + b * 2];
    total += lc + lo + 0.01f * smv;
  }
  total *= 0.25f;
  float fsy = 0.f, fsx = 0.f;
  for (int s = 0; s < 16; ++s) { fsy += accg[32 + s * 2]; fsx += accg[33 + s * 2]; }
  const float cnt = 4.f * 384.f * 63.f * 64.f;
  float ly = fsy / cnt * (1.f / 384.f);
  float lx = fsx / cnt * (1.f / 384.f);
  out[131072] = total + 0.09f * 0.5f * (ly + lx);
}

extern "C" void kernel_launch(void* const* d_in, const int* in_sizes, int n_in,
                              void* d_out, int out_size, void* d_ws, size_t ws_size,
                              hipStream_t stream) {
  const float* feat = (const float*)d_in[0];
  const float* gcn_w0 = (const float*)d_in[1];
  const float* gcn_b0 = (const float*)d_in[2];
  const float* gcn_w = (const float*)d_in[3];
  const float* gcn_b = (const float*)d_in[4];
  const float* ln_g = (const float*)d_in[5];
  const float* ln_b = (const float*)d_in[6];
  const float* res_w = (const float*)d_in[7];
  const float* res_b = (const float*)d_in[8];
  const float* res_ln_g = (const float*)d_in[9];
  const float* res_ln_b = (const float*)d_in[10];
  const float* mlp_w1 = (const float*)d_in[11];
  const float* mlp_b1 = (const float*)d_in[12];
  const float* mlp_ln_g = (const float*)d_in[13];
  const float* mlp_ln_b = (const float*)d_in[14];
  const float* mlp_w2 = (const float*)d_in[15];
  const float* mlp_b2 = (const float*)d_in[16];
  const float* sm_w1 = (const float*)d_in[17];
  const float* sm_b1 = (const float*)d_in[18];
  const float* sm_g1 = (const float*)d_in[19];
  const float* sm_bb1 = (const float*)d_in[20];
  const float* sm_w2 = (const float*)d_in[21];
  const float* sm_b2 = (const float*)d_in[22];
  const float* sm_g2 = (const float*)d_in[23];
  const float* sm_bb2 = (const float*)d_in[24];
  const float* ec_w1 = (const float*)d_in[25];
  const float* ec_b1 = (const float*)d_in[26];
  const float* ec_gn_g = (const float*)d_in[27];
  const float* ec_gn_b = (const float*)d_in[28];
  const float* ec_w2 = (const float*)d_in[29];
  const float* ec_b2 = (const float*)d_in[30];

  float* out = (float*)d_out;
  float* ws = (float*)d_ws;
  float* acc = ws;                       // 512 floats
  float* xw = ws + 512;                  // B*T*64
  float* xbuf = xw + 1048576;            // B*T*64
  float* resbuf = xbuf + 1048576;        // B*T*64
  float* Sp = resbuf + 1048576;          // B*K*T
  float* eraw = Sp + 131072;             // B*T*32 (pixel-major)
  float* ew = eraw + 524288;             // B*T
  short* wqb = (short*)(ew + 16384);     // 110592 shorts (bf16)
  short* wb = wqb + 110592;              // 49152 shorts (bf16, frag order)
  short* fb = wb + 49152;                // B*T*384 shorts (bf16 feat)
  float* S = out;                        // (B,T,K) straight into d_out

  k_featbf<<<3072, 256, 0, stream>>>(feat, fb);
  k_wq<<<432, 256, 0, stream>>>(ec_w1, wqb, acc);
  k_wb<<<24, 256, 0, stream>>>(gcn_w0, res_w, wb);

  k_gemm0<<<256, 256, 0, stream>>>(fb, wb, gcn_w0, res_w, res_b, res_ln_g,
                                   res_ln_b, xw, resbuf);
  k_stencil<<<B_ * T_ / 4, 256, 0, stream>>>(xw, gcn_b0, ln_g, ln_b, resbuf, xbuf);
  for (int i = 1; i < 4; ++i) {
    k_gemm64<<<B_ * T_ / 32, 256, 0, stream>>>(xbuf, gcn_w + (i - 1) * 4096, xw);
    k_stencil<<<B_ * T_ / 4, 256, 0, stream>>>(xw, gcn_b + (i - 1) * 64,
                                               ln_g + i * 64, ln_b + i * 64, xbuf,
                                               xbuf);
  }
  k_mlp<<<B_ * T_ / 4, 256, 0, stream>>>(xbuf, mlp_w1, mlp_b1, mlp_ln_g, mlp_ln_b,
                                         mlp_w2, mlp_b2, S, Sp);

  k_cutss<<<B_ * T_ / 32, 256, 0, stream>>>(S, acc);
  k_sm<<<32, 256, 0, stream>>>(Sp, sm_w1, sm_b1, sm_g1, sm_bb1, sm_w2, sm_b2, sm_g2,
                               sm_bb2, acc);

  k_ecconv<<<256, 256, 0, stream>>>(fb, wqb, ec_b1, eraw, acc);
  k_ecfinal<<<B_ * T_ / 256, 256, 0, stream>>>(eraw, acc, ec_gn_g, ec_gn_b, ec_w2,
                                               ec_b2, ew);
  k_fsloss<<<512, 256, 0, stream>>>(fb, ew, acc);
  k_final<<<1, 64, 0, stream>>>(acc, out);
}

// Round 7
// 138.541 us; speedup vs baseline: 2.6853x; 1.6410x over previous
//
#include <hip/hip_runtime.h>
#include <hip/hip_bf16.h>

// ---------------------------------------------------------------------------
// DeepCut fused pipeline. B=4, T=4096 (64x64), D=384, K=8, CH=64, NL=4.
// Graph = 5x5 box stencil, separable: A@x = u(i)u(j) * S_ii u(ii) S_jj u(jj) x.
// gemm0 + edge-conv bf16 MFMA; GCN layers/LN/softmax/losses fp32.
// 10 launches: prep, gemm0, layer x3, st4mlp, lossmix, ecfinal, fsloss, final.
// Accumulator map (512 floats, zeroed by k_prep):
//  [0..15] cut num  [16..31] cut den  [32..63] fs partials
//  [64..127] ec GN stats  [128..383] SS  [384..391] sm loss
// ---------------------------------------------------------------------------

#define B_ 4
#define T_ 4096
#define D_ 384
#define K_ 8
#define CH_ 64

typedef __attribute__((ext_vector_type(8))) short short8b;
typedef __attribute__((ext_vector_type(4))) float f32x4;

__device__ __forceinline__ float wred(float v) {
#pragma unroll
  for (int off = 32; off > 0; off >>= 1) v += __shfl_xor(v, off);
  return v;
}

__device__ __forceinline__ short bf16rne(float f) {
  unsigned u = __float_as_uint(f);
  unsigned r = (u + 0x7FFFu + ((u >> 16) & 1u)) >> 16;
  return (short)r;
}

__device__ __forceinline__ float bf2f(short s) {
  return __uint_as_float(((unsigned)(unsigned short)s) << 16);
}

__device__ __forceinline__ float uval(int i) {
  int c = (i < 2 ? i : 2) + ((63 - i) < 2 ? (63 - i) : 2) + 1;
  return rsqrtf((float)c);
}

// ---- prep: feat->bf16 (blk<3072) | ec_w1 transpose (3072..3503) | wb (3504..)
__global__ __launch_bounds__(256) void k_prep(const float* __restrict__ feat,
                                              const float* __restrict__ ecw1,
                                              const float* __restrict__ w0,
                                              const float* __restrict__ resw,
                                              short* __restrict__ fb,
                                              short* __restrict__ wq,
                                              short* __restrict__ wb,
                                              float* __restrict__ accg) {
  int blk = blockIdx.x;
  if (blk == 0 && threadIdx.x < 256) {
    accg[threadIdx.x] = 0.f;
    accg[threadIdx.x + 256] = 0.f;
  }
  if (blk < 3072) {
    int tid = blk * 256 + threadIdx.x;
    const float4* s = (const float4*)feat + (size_t)tid * 2;
    float4 a = s[0], b = s[1];
    short8b v;
    v[0] = bf16rne(a.x); v[1] = bf16rne(a.y); v[2] = bf16rne(a.z); v[3] = bf16rne(a.w);
    v[4] = bf16rne(b.x); v[5] = bf16rne(b.y); v[6] = bf16rne(b.z); v[7] = bf16rne(b.w);
    *(short8b*)(fb + (size_t)tid * 8) = v;
  } else if (blk < 3504) {
    int idx = (blk - 3072) * 256 + threadIdx.x;  // < 110592
    int q = idx % 9;
    int rest = idx / 9;
    int d = rest % 384;
    int o = rest / 384;
    wq[((size_t)(q * 32 + o)) * 384 + d] = bf16rne(ecw1[idx]);
  } else {
    int u = (blk - 3504) * 256 + threadIdx.x;  // < 6144
    int l = u & 63, f = (u >> 6) & 7, s = u >> 9;
    int c = f * 16 + (l & 15);
    int k0 = s * 32 + ((l >> 4) << 3);
    const float* src = (c < 64) ? (w0 + c) : (resw + (c - 64));
    short8b v;
#pragma unroll
    for (int j = 0; j < 8; ++j) v[j] = bf16rne(src[(size_t)(k0 + j) * 64]);
    *(short8b*)(wb + (size_t)u * 8) = v;
  }
}

// ---- layer-0 GEMM via bf16 MFMA: block = 64 rows x 128 cols (w0|resw), K=384
__global__ __launch_bounds__(256) void k_gemm0(
    const short* __restrict__ fb, const short* __restrict__ wb,
    const float* __restrict__ w0, const float* __restrict__ resw,
    const float* __restrict__ resb, const float* __restrict__ resg,
    const float* __restrict__ reslb, float* __restrict__ xw,
    float* __restrict__ res) {
  __shared__ __align__(16) short Ab[24576];
  __shared__ __align__(16) short Bb[49152];
  int tid = threadIdx.x;
  int row0 = blockIdx.x * 64;
  const short8b* wb8 = (const short8b*)wb;
  short8b* Bb8 = (short8b*)Bb;
#pragma unroll
  for (int it = 0; it < 24; ++it) Bb8[tid + it * 256] = wb8[tid + it * 256];
  short8b* Ab8 = (short8b*)Ab;
#pragma unroll
  for (int it = 0; it < 12; ++it) {
    int u = it * 256 + tid;
    int l = u & 63, w = (u >> 6) & 3, s = u >> 8;
    int row = w * 16 + (l & 15);
    int k = s * 32 + ((l >> 4) << 3);
    Ab8[u] = *(const short8b*)(fb + (size_t)(row0 + row) * 384 + k);
  }
  __syncthreads();
  int wid = tid >> 6, lane = tid & 63;
  f32x4 acc[8];
#pragma unroll
  for (int f = 0; f < 8; ++f) acc[f] = (f32x4){0.f, 0.f, 0.f, 0.f};
#pragma unroll
  for (int s = 0; s < 12; ++s) {
    short8b av = Ab8[(s * 4 + wid) * 64 + lane];
#pragma unroll
    for (int f = 0; f < 8; ++f) {
      short8b bv = Bb8[(s * 8 + f) * 64 + lane];
      acc[f] = __builtin_amdgcn_mfma_f32_16x16x32_bf16(av, bv, acc[f], 0, 0, 0);
    }
  }
  int g = lane >> 4, ln = lane & 15;
  float pw1[4], pw2[4], rw1[4], rw2[4], rb[4], rgam[4], rbet[4];
#pragma unroll
  for (int f = 0; f < 4; ++f) {
    int c = f * 16 + ln;
    pw1[f] = w0[384 * 64 + c];  pw2[f] = w0[385 * 64 + c];
    rw1[f] = resw[384 * 64 + c]; rw2[f] = resw[385 * 64 + c];
    rb[f] = resb[c]; rgam[f] = resg[c]; rbet[f] = reslb[c];
  }
#pragma unroll
  for (int r = 0; r < 4; ++r) {
    int grow = row0 + wid * 16 + g * 4 + r;
    int t = grow & (T_ - 1);
    float px = (float)(t & 63) * (1.f / 63.f);
    float py = (float)(t >> 6) * (1.f / 63.f);
    float rv[4];
    float s1 = 0.f, s2 = 0.f;
#pragma unroll
    for (int f = 0; f < 4; ++f) {
      float xv = acc[f][r] + px * pw1[f] + py * pw2[f];
      xw[(size_t)grow * 64 + f * 16 + ln] = xv;
      float v = acc[4 + f][r] + px * rw1[f] + py * rw2[f] + rb[f];
      rv[f] = v;
      s1 += v;
      s2 = fmaf(v, v, s2);
    }
#pragma unroll
    for (int off = 1; off < 16; off <<= 1) {
      s1 += __shfl_xor(s1, off);
      s2 += __shfl_xor(s2, off);
    }
    float mean = s1 * (1.f / 64.f);
    float var = s2 * (1.f / 64.f) - mean * mean;
    float inv = rsqrtf(var + 1e-5f);
#pragma unroll
    for (int f = 0; f < 4; ++f)
      res[(size_t)grow * 64 + f * 16 + ln] = (rv[f] - mean) * inv * rgam[f] + rbet[f];
  }
}

// ---- fused layer: separable stencil + LN + ELU + residual, then X@W ----
// block = 32 rows (half an image line); thread = (c = tid&63, jg = tid>>6), 8 j's.
__global__ __launch_bounds__(256) void k_layer(
    const float* __restrict__ xw_in, const float* __restrict__ W,
    const float* __restrict__ bias, const float* __restrict__ lng,
    const float* __restrict__ lnb, const float* __restrict__ resid,
    float* __restrict__ xout, float* __restrict__ xw_out) {
  __shared__ float sx[32 * 64];   // 8KB
  __shared__ float sW[64 * 64];   // 16KB
  int tid = threadIdx.x;
  int t0 = blockIdx.x * 32;
  int b = t0 >> 12, i = (t0 >> 6) & 63;
  const float4* w4 = (const float4*)W;
  float4* sW4 = (float4*)sW;
#pragma unroll
  for (int l = 0; l < 4; ++l) sW4[tid + l * 256] = w4[tid + l * 256];
  int c = tid & 63, jg = tid >> 6;
  int jb = (t0 & 63) + jg * 8;
  float ui = uval(i);
  float acc[8];
#pragma unroll
  for (int m = 0; m < 8; ++m) acc[m] = 0.f;
  float uw[12];
#pragma unroll
  for (int d = 0; d < 12; ++d) {
    int jj = jb - 2 + d;
    uw[d] = (jj >= 0 && jj < 64) ? uval(jj) : 0.f;
  }
#pragma unroll
  for (int di = -2; di <= 2; ++di) {
    int ii = i + di;
    if (ii < 0 || ii > 63) continue;
    float wi = uval(ii);
    const float* src = xw_in + ((size_t)((b << 12) + (ii << 6))) * 64 + c;
    float v[12];
#pragma unroll
    for (int d = 0; d < 12; ++d) {
      int jj = jb - 2 + d;
      v[d] = (jj >= 0 && jj < 64) ? src[jj * 64] : 0.f;
    }
#pragma unroll
    for (int m = 0; m < 8; ++m) {
      float t = v[m] * uw[m] + v[m + 1] * uw[m + 1] + v[m + 2] * uw[m + 2] +
                v[m + 3] * uw[m + 3] + v[m + 4] * uw[m + 4];
      acc[m] = fmaf(wi, t, acc[m]);
    }
  }
  float bc = bias[c], gam = lng[c], bet = lnb[c];
#pragma unroll
  for (int m = 0; m < 8; ++m) {
    int lrow = jg * 8 + m;
    float h = ui * uval(jb + m) * acc[m] + bc;
    float mean = wred(h) * (1.f / 64.f);
    float dd = h - mean;
    float var = wred(dd * dd) * (1.f / 64.f);
    float n = dd * rsqrtf(var + 1e-5f) * gam + bet;
    float e = n > 0.f ? n : (expf(n) - 1.f);
    float xv = e + resid[(size_t)(t0 + lrow) * 64 + c];
    xout[(size_t)(t0 + lrow) * 64 + c] = xv;
    sx[lrow * 64 + c] = xv;
  }
  __syncthreads();
  float a[8];
#pragma unroll
  for (int m = 0; m < 8; ++m) a[m] = 0.f;
#pragma unroll
  for (int kq = 0; kq < 16; ++kq) {
    float4 fv[8];
#pragma unroll
    for (int m = 0; m < 8; ++m)
      fv[m] = *(const float4*)&sx[(jg * 8 + m) * 64 + kq * 4];
#pragma unroll
    for (int dk = 0; dk < 4; ++dk) {
      float wv = sW[(kq * 4 + dk) * 64 + c];
#pragma unroll
      for (int m = 0; m < 8; ++m)
        a[m] = fmaf(((const float*)&fv[m])[dk], wv, a[m]);
    }
  }
#pragma unroll
  for (int m = 0; m < 8; ++m)
    xw_out[(size_t)(t0 + jg * 8 + m) * 64 + c] = a[m];
}

// ---- fused final stencil + MLP head (h1=elu(LN(x@w1+b1)); S=softmax(h1@w2+b2))
__global__ __launch_bounds__(256) void k_st4mlp(
    const float* __restrict__ xw_in, const float* __restrict__ bias,
    const float* __restrict__ lng, const float* __restrict__ lnb,
    const float* __restrict__ resid, const float* __restrict__ w1,
    const float* __restrict__ b1, const float* __restrict__ mlng,
    const float* __restrict__ mlnb, const float* __restrict__ w2,
    const float* __restrict__ b2, float* __restrict__ S, float* __restrict__ Sp) {
  __shared__ float sx[32 * 64];
  __shared__ float sW[64 * 64];
  __shared__ float sh[32 * 64];
  int tid = threadIdx.x;
  int t0 = blockIdx.x * 32;
  int b = t0 >> 12, i = (t0 >> 6) & 63;
  const float4* w4 = (const float4*)w1;
  float4* sW4 = (float4*)sW;
#pragma unroll
  for (int l = 0; l < 4; ++l) sW4[tid + l * 256] = w4[tid + l * 256];
  int c = tid & 63, jg = tid >> 6;
  int jb = (t0 & 63) + jg * 8;
  float ui = uval(i);
  float acc[8];
#pragma unroll
  for (int m = 0; m < 8; ++m) acc[m] = 0.f;
  float uw[12];
#pragma unroll
  for (int d = 0; d < 12; ++d) {
    int jj = jb - 2 + d;
    uw[d] = (jj >= 0 && jj < 64) ? uval(jj) : 0.f;
  }
#pragma unroll
  for (int di = -2; di <= 2; ++di) {
    int ii = i + di;
    if (ii < 0 || ii > 63) continue;
    float wi = uval(ii);
    const float* src = xw_in + ((size_t)((b << 12) + (ii << 6))) * 64 + c;
    float v[12];
#pragma unroll
    for (int d = 0; d < 12; ++d) {
      int jj = jb - 2 + d;
      v[d] = (jj >= 0 && jj < 64) ? src[jj * 64] : 0.f;
    }
#pragma unroll
    for (int m = 0; m < 8; ++m) {
      float t = v[m] * uw[m] + v[m + 1] * uw[m + 1] + v[m + 2] * uw[m + 2] +
                v[m + 3] * uw[m + 3] + v[m + 4] * uw[m + 4];
      acc[m] = fmaf(wi, t, acc[m]);
    }
  }
  float bc = bias[c], gam = lng[c], bet = lnb[c];
#pragma unroll
  for (int m = 0; m < 8; ++m) {
    int lrow = jg * 8 + m;
    float h = ui * uval(jb + m) * acc[m] + bc;
    float mean = wred(h) * (1.f / 64.f);
    float dd = h - mean;
    float var = wred(dd * dd) * (1.f / 64.f);
    float n = dd * rsqrtf(var + 1e-5f) * gam + bet;
    float e = n > 0.f ? n : (expf(n) - 1.f);
    sx[lrow * 64 + c] = e + resid[(size_t)(t0 + lrow) * 64 + c];
  }
  __syncthreads();
  // h1 = elu(LN(x@w1 + b1))
  float a[8];
#pragma unroll
  for (int m = 0; m < 8; ++m) a[m] = 0.f;
#pragma unroll
  for (int kq = 0; kq < 16; ++kq) {
    float4 fv[8];
#pragma unroll
    for (int m = 0; m < 8; ++m)
      fv[m] = *(const float4*)&sx[(jg * 8 + m) * 64 + kq * 4];
#pragma unroll
    for (int dk = 0; dk < 4; ++dk) {
      float wv = sW[(kq * 4 + dk) * 64 + c];
#pragma unroll
      for (int m = 0; m < 8; ++m)
        a[m] = fmaf(((const float*)&fv[m])[dk], wv, a[m]);
    }
  }
  float mb = b1[c], mgam = mlng[c], mbet = mlnb[c];
#pragma unroll
  for (int m = 0; m < 8; ++m) {
    float h = a[m] + mb;
    float mean = wred(h) * (1.f / 64.f);
    float dd = h - mean;
    float var = wred(dd * dd) * (1.f / 64.f);
    float n = dd * rsqrtf(var + 1e-5f) * mgam + mbet;
    sh[(jg * 8 + m) * 64 + c] = n > 0.f ? n : (expf(n) - 1.f);
  }
  __syncthreads();
  // logits + softmax: thread = (k = tid&7, j = tid>>3)
  int k = tid & 7, j = tid >> 3;
  float lg = b2[k];
#pragma unroll 8
  for (int u = 0; u < 64; ++u) {
    int cc = (u + j * 8) & 63;
    lg = fmaf(sh[j * 64 + cc], w2[cc * 8 + k], lg);
  }
  float mx = lg;
  mx = fmaxf(mx, __shfl_xor(mx, 1));
  mx = fmaxf(mx, __shfl_xor(mx, 2));
  mx = fmaxf(mx, __shfl_xor(mx, 4));
  float ex = expf(lg - mx);
  float sum = ex;
  sum += __shfl_xor(sum, 1);
  sum += __shfl_xor(sum, 2);
  sum += __shfl_xor(sum, 4);
  float val = ex / sum;
  int grow = t0 + j;
  int t = grow & (T_ - 1);
  S[(size_t)grow * 8 + k] = val;
  Sp[((size_t)((b << 3) + k) << 12) + t] = val;
}

// ---- lossmix: cut+SS (blk 0..511) | sm (512..543) | ecconv (544..799) ----
__global__ __launch_bounds__(256) void k_lossmix(
    const float* __restrict__ S, const float* __restrict__ Sp,
    const float* __restrict__ smw1, const float* __restrict__ smb1,
    const float* __restrict__ smg1, const float* __restrict__ smbb1,
    const float* __restrict__ smw2, const float* __restrict__ smb2,
    const float* __restrict__ smg2, const float* __restrict__ smbb2,
    const short* __restrict__ fb, const short* __restrict__ wq,
    const float* __restrict__ ecb1, float* __restrict__ eraw,
    float* __restrict__ accg) {
  __shared__ __align__(16) char smem[32832];
  int blk = blockIdx.x;
  if (blk < 512) {
    // ---- normalized cut ----
    {
      int k = threadIdx.x & 7;
      int tl = threadIdx.x >> 3;
      int gid = blk * 32 + tl;
      int b = gid >> 12, t = gid & (T_ - 1);
      int i = t >> 6, j = t & 63;
      float ui = uval(i), uj = uval(j);
      float as = 0.f, sui = 0.f, suj = 0.f;
#pragma unroll
      for (int di = -2; di <= 2; ++di) {
        int ii = i + di;
        if (ii < 0 || ii > 63) continue;
        float wi = uval(ii);
        sui += wi;
#pragma unroll
        for (int dj = -2; dj <= 2; ++dj) {
          int jj = j + dj;
          if (jj < 0 || jj > 63) continue;
          as = fmaf(wi * uval(jj),
                    S[((size_t)((b << 12) + (ii << 6) + jj)) * 8 + k], as);
        }
      }
#pragma unroll
      for (int dj = -2; dj <= 2; ++dj) {
        int jj = j + dj;
        if (jj >= 0 && jj <= 63) suj += uval(jj);
      }
      as *= ui * uj;
      float sv = S[(size_t)gid * 8 + k];
      float degA = ui * uj * sui * suj;
      float numv = wred(sv * as);
      float denv = wred(sv * sv * degA);
      float* lds = (float*)smem;
      int wid = threadIdx.x >> 6, lane = threadIdx.x & 63;
      if (lane == 0) { lds[wid * 2] = numv; lds[wid * 2 + 1] = denv; }
      __syncthreads();
      if (threadIdx.x == 0) {
        int slot = b * 4 + (blk & 3);
        atomicAdd(&accg[slot], lds[0] + lds[2] + lds[4] + lds[6]);
        atomicAdd(&accg[16 + slot], lds[1] + lds[3] + lds[5] + lds[7]);
      }
    }
    if (blk < 32) {
      __syncthreads();
      int b = blk >> 3, chunk = blk & 7;
      int wid = threadIdx.x >> 6, lane = threadIdx.x & 63;
      int kk = lane >> 3, ll = lane & 7;
      int t0 = chunk * 512 + wid * 128;
      float a = 0.f;
      const float* Sb = S + ((size_t)b << 12) * 8;
      for (int it = 0; it < 128; ++it) {
        const float* sr = Sb + (size_t)(t0 + it) * 8;
        a = fmaf(sr[kk], sr[ll], a);
      }
      float* lds2 = (float*)smem;
      lds2[threadIdx.x] = a;
      __syncthreads();
      if (threadIdx.x < 64) {
        float s = lds2[threadIdx.x] + lds2[threadIdx.x + 64] +
                  lds2[threadIdx.x + 128] + lds2[threadIdx.x + 192];
        atomicAdd(&accg[128 + b * 64 + threadIdx.x], s);
      }
    }
  } else if (blk < 544) {
    // ---- spatial smoothness ----
    float* p0 = (float*)smem;
    float* p1 = p0 + 4096;
    float* red = p1 + 4096;
    int bk = blk - 512, b = bk >> 3, k = bk & 7;
    const float4* src = (const float4*)(Sp + (size_t)bk * 4096);
    float4* d0 = (float4*)p0;
    for (int i2 = threadIdx.x; i2 < 1024; i2 += 256) d0[i2] = src[i2];
    float W1[9], W2[9];
#pragma unroll
    for (int q = 0; q < 9; ++q) { W1[q] = smw1[k * 9 + q]; W2[q] = smw2[k * 9 + q]; }
    __syncthreads();
    int wid = threadIdx.x >> 6, lane = threadIdx.x & 63;
    float y[16];
    float s1 = 0.f, s2 = 0.f;
#pragma unroll
    for (int v = 0; v < 16; ++v) {
      int p = v * 256 + threadIdx.x;
      int i2 = p >> 6, j2 = p & 63;
      float a = smb1[k];
#pragma unroll
      for (int dy = 0; dy < 3; ++dy) {
        int ii = i2 + dy - 1;
        if (ii < 0 || ii > 63) continue;
#pragma unroll
        for (int dx = 0; dx < 3; ++dx) {
          int jj = j2 + dx - 1;
          if (jj < 0 || jj > 63) continue;
          a = fmaf(W1[dy * 3 + dx], p0[(ii << 6) + jj], a);
        }
      }
      y[v] = a;
      s1 += a;
      s2 = fmaf(a, a, s2);
    }
    s1 = wred(s1); s2 = wred(s2);
    if (lane == 0) { red[wid * 2] = s1; red[wid * 2 + 1] = s2; }
    __syncthreads();
    float mean = (red[0] + red[2] + red[4] + red[6]) * (1.f / 4096.f);
    float var = (red[1] + red[3] + red[5] + red[7]) * (1.f / 4096.f) - mean * mean;
    float inv = rsqrtf(var + 1e-5f) * smg1[k];
    float sh = smbb1[k];
    __syncthreads();
#pragma unroll
    for (int v = 0; v < 16; ++v) {
      int p = v * 256 + threadIdx.x;
      p1[p] = fmaxf((y[v] - mean) * inv + sh, 0.f);
    }
    __syncthreads();
    s1 = 0.f; s2 = 0.f;
#pragma unroll
    for (int v = 0; v < 16; ++v) {
      int p = v * 256 + threadIdx.x;
      int i2 = p >> 6, j2 = p & 63;
      float a = smb2[k];
#pragma unroll
      for (int dy = 0; dy < 3; ++dy) {
        int ii = i2 + dy - 1;
        if (ii < 0 || ii > 63) continue;
#pragma unroll
        for (int dx = 0; dx < 3; ++dx) {
          int jj = j2 + dx - 1;
          if (jj < 0 || jj > 63) continue;
          a = fmaf(W2[dy * 3 + dx], p1[(ii << 6) + jj], a);
        }
      }
      y[v] = a;
      s1 += a;
      s2 = fmaf(a, a, s2);
    }
    s1 = wred(s1); s2 = wred(s2);
    if (lane == 0) { red[wid * 2] = s1; red[wid * 2 + 1] = s2; }
    __syncthreads();
    float mean2 = (red[0] + red[2] + red[4] + red[6]) * (1.f / 4096.f);
    float var2 = (red[1] + red[3] + red[5] + red[7]) * (1.f / 4096.f) - mean2 * mean2;
    float inv2 = rsqrtf(var2 + 1e-5f) * smg2[k];
    float sh2 = smbb2[k];
    float sd = 0.f;
#pragma unroll
    for (int v = 0; v < 16; ++v) {
      int p = v * 256 + threadIdx.x;
      float sm = (y[v] - mean2) * inv2 + sh2;
      float dd = sm - p0[p];
      sd = fmaf(dd, dd, sd);
    }
    sd = wred(sd);
    __syncthreads();
    if (lane == 0) red[wid] = sd;
    __syncthreads();
    if (threadIdx.x == 0)
      atomicAdd(&accg[384 + b * 2 + (bk & 1)],
                (red[0] + red[1] + red[2] + red[3]) * (1.f / 32768.f));
  } else {
    // ---- edge conv via bf16 MFMA ----
    short* Abuf = (short*)smem;              // 3*67*32 = 6432 shorts
    short* Wbuf = Abuf + 6432;               // 9*32*32 = 9216 shorts
    float* sW1 = (float*)(Wbuf + 9216);      // 4*32
    float* sW2 = sW1 + 128;                  // 4*32
    int blk2 = blk - 544;
    int b = blk2 >> 6, i = blk2 & 63;
    int tid = threadIdx.x;
    int wid = tid >> 6, lane = tid & 63;
    int m = lane & 15, kg = lane >> 4;
    if (tid < 36) {
      int zkg = tid & 3, sl = (tid >> 2) % 3, r = tid / 12;
      int slot = sl == 0 ? 0 : (sl == 1 ? 65 : 66);
      *(short8b*)&Abuf[(r * 67 + slot) * 32 + zkg * 8] = (short8b)0;
    }
    f32x4 acc0 = {0.f, 0.f, 0.f, 0.f};
    f32x4 acc1 = {0.f, 0.f, 0.f, 0.f};
    int abase = (wid * 16 + m) * 32 + kg * 8;
    int bbase = m * 32 + kg * 8;
    for (int c = 0; c < 12; ++c) {
      __syncthreads();
#pragma unroll
      for (int s = 0; s < 3; ++s) {
        int cid = tid + (s << 8);
        int akg = cid & 3, px = (cid >> 2) & 63, r = cid >> 8;
        int ii = i + r - 1;
        short8b v = (short8b)0;
        if (ii >= 0 && ii < 64)
          v = *(const short8b*)(fb +
                ((size_t)((b << 12) + (ii << 6) + px)) * D_ + c * 32 + akg * 8);
        *(short8b*)&Abuf[(r * 67 + px + 1) * 32 + akg * 8] = v;
      }
      for (int l = tid; l < 1152; l += 256) {
        int wkg = l & 3, oo = (l >> 2) & 31, q = l >> 7;
        short8b wv =
            *(const short8b*)(wq + ((size_t)(q * 32 + oo)) * D_ + c * 32 + wkg * 8);
        *(short8b*)&Wbuf[(q * 32 + oo) * 32 + wkg * 8] = wv;
      }
      __syncthreads();
#pragma unroll
      for (int q = 0; q < 9; ++q) {
        short8b av = *(const short8b*)&Abuf[abase + ((q / 3) * 67 + (q % 3)) * 32];
        short8b bv0 = *(const short8b*)&Wbuf[bbase + q * 1024];
        short8b bv1 = *(const short8b*)&Wbuf[bbase + q * 1024 + 512];
        acc0 = __builtin_amdgcn_mfma_f32_16x16x32_bf16(av, bv0, acc0, 0, 0, 0);
        acc1 = __builtin_amdgcn_mfma_f32_16x16x32_bf16(av, bv1, acc1, 0, 0, 0);
      }
    }
    int o0 = m, o1 = 16 + m;
    float bs0 = ecb1[o0], bs1 = ecb1[o1];
    float s1a = 0.f, s2a = 0.f, s1b = 0.f, s2b = 0.f;
    int jbase = wid * 16 + kg * 4;
#pragma unroll
    for (int rg = 0; rg < 4; ++rg) {
      float v0 = acc0[rg] + bs0;
      float v1 = acc1[rg] + bs1;
      int j = jbase + rg;
      size_t px = ((size_t)((b << 12) + (i << 6) + j)) * 32;
      eraw[px + o0] = v0;
      eraw[px + o1] = v1;
      s1a += v0; s2a = fmaf(v0, v0, s2a);
      s1b += v1; s2b = fmaf(v1, v1, s2b);
    }
    s1a += __shfl_xor(s1a, 16); s1a += __shfl_xor(s1a, 32);
    s2a += __shfl_xor(s2a, 16); s2a += __shfl_xor(s2a, 32);
    s1b += __shfl_xor(s1b, 16); s1b += __shfl_xor(s1b, 32);
    s2b += __shfl_xor(s2b, 16); s2b += __shfl_xor(s2b, 32);
    if (lane < 16) {
      sW1[wid * 32 + lane] = s1a; sW2[wid * 32 + lane] = s2a;
      sW1[wid * 32 + lane + 16] = s1b; sW2[wid * 32 + lane + 16] = s2b;
    }
    __syncthreads();
    if (tid < 32) {
      float t1 = sW1[tid] + sW1[32 + tid] + sW1[64 + tid] + sW1[96 + tid];
      float t2 = sW2[tid] + sW2[32 + tid] + sW2[64 + tid] + sW2[96 + tid];
      t1 += __shfl_xor(t1, 1); t1 += __shfl_xor(t1, 2);
      t2 += __shfl_xor(t2, 1); t2 += __shfl_xor(t2, 2);
      if ((tid & 3) == 0) {
        atomicAdd(&accg[64 + b * 16 + (tid >> 2) * 2], t1);
        atomicAdd(&accg[64 + b * 16 + (tid >> 2) * 2 + 1], t2);
      }
    }
  }
}

// ---- GN + relu + 1x1 conv + sigmoid -> ew (B,T) ----
__global__ __launch_bounds__(256) void k_ecfinal(
    const float* __restrict__ eraw, const float* __restrict__ accg,
    const float* __restrict__ gng, const float* __restrict__ gnb,
    const float* __restrict__ w2, const float* __restrict__ b2,
    float* __restrict__ ew) {
  __shared__ float st[16];
  int idx = blockIdx.x * 256 + threadIdx.x;
  int b = idx >> 12;
  if (threadIdx.x < 16) st[threadIdx.x] = accg[64 + b * 16 + threadIdx.x];
  __syncthreads();
  float a = b2[0];
  const float4* er = (const float4*)(eraw + (size_t)idx * 32);
#pragma unroll
  for (int oq = 0; oq < 8; ++oq) {
    float mean = st[oq * 2] * (1.f / 16384.f);
    float var = st[oq * 2 + 1] * (1.f / 16384.f) - mean * mean;
    float inv = rsqrtf(var + 1e-5f);
    float4 e = er[oq];
    int o = oq * 4;
    float v0 = (e.x - mean) * inv * gng[o + 0] + gnb[o + 0];
    float v1 = (e.y - mean) * inv * gng[o + 1] + gnb[o + 1];
    float v2 = (e.z - mean) * inv * gng[o + 2] + gnb[o + 2];
    float v3 = (e.w - mean) * inv * gng[o + 3] + gnb[o + 3];
    a = fmaf(fmaxf(v0, 0.f), w2[o + 0], a);
    a = fmaf(fmaxf(v1, 0.f), w2[o + 1], a);
    a = fmaf(fmaxf(v2, 0.f), w2[o + 2], a);
    a = fmaf(fmaxf(v3, 0.f), w2[o + 3], a);
  }
  ew[idx] = 1.f / (1.f + expf(-a));
}

// ---- feature-smoothness gradient sums (bf16 feat); scattered atomics ----
__global__ __launch_bounds__(256) void k_fsloss(const short* __restrict__ fb,
                                                const float* __restrict__ ew,
                                                float* __restrict__ accg) {
  float sy = 0.f, sx = 0.f;
  const int N = B_ * T_ * 48;
  for (int idx = blockIdx.x * 256 + threadIdx.x; idx < N; idx += gridDim.x * 256) {
    int d8 = idx % 48;
    int rt = idx / 48;
    int t = rt & (T_ - 1);
    int i = t >> 6, j = t & 63;
    const short8b* fp = (const short8b*)(fb + (size_t)rt * D_) + d8;
    short8b f0 = *fp;
    if (i < 63) {
      short8b f1 = fp[64 * 48];
      float w = ew[rt + 64];
      float a = 0.f;
#pragma unroll
      for (int u = 0; u < 8; ++u) {
        float d = bf2f(f1[u]) - bf2f(f0[u]);
        a = fmaf(d, d, a);
      }
      sy += w * a;
    }
    if (j < 63) {
      short8b f1 = fp[48];
      float w = ew[rt + 1];
      float a = 0.f;
#pragma unroll
      for (int u = 0; u < 8; ++u) {
        float d = bf2f(f1[u]) - bf2f(f0[u]);
        a = fmaf(d, d, a);
      }
      sx += w * a;
    }
  }
  sy = wred(sy);
  sx = wred(sx);
  __shared__ float lds[8];
  int wid = threadIdx.x >> 6, lane = threadIdx.x & 63;
  if (lane == 0) { lds[wid * 2] = sy; lds[wid * 2 + 1] = sx; }
  __syncthreads();
  if (threadIdx.x == 0) {
    int slot = 32 + (blockIdx.x & 15) * 2;
    atomicAdd(&accg[slot], lds[0] + lds[2] + lds[4] + lds[6]);
    atomicAdd(&accg[slot + 1], lds[1] + lds[3] + lds[5] + lds[7]);
  }
}

// ---- final scalar assembly ----
__global__ void k_final(const float* __restrict__ accg, float* __restrict__ out) {
  if (threadIdx.x != 0 || blockIdx.x != 0) return;
  float total = 0.f;
  for (int b = 0; b < 4; ++b) {
    const float* SSb = accg + 128 + b * 64;
    float ssq = 0.f;
    for (int v = 0; v < 64; ++v) ssq += SSb[v] * SSb[v];
    float ssn = sqrtf(ssq);
    float tgt = 1.f / (sqrtf(8.f) + 1e-6f);
    float inv = 1.f / (ssn + 1e-6f);
    float lo = 0.f;
    for (int kk = 0; kk < 8; ++kk)
      for (int ll = 0; ll < 8; ++ll) {
        float dd = SSb[kk * 8 + ll] * inv - (kk == ll ? tgt : 0.f);
        lo += dd * dd;
      }
    lo = sqrtf(lo);
    float num = accg[b * 4] + accg[b * 4 + 1] + accg[b * 4 + 2] + accg[b * 4 + 3];
    float den = accg[16 + b * 4] + accg[16 + b * 4 + 1] + accg[16 + b * 4 + 2] +
                accg[16 + b * 4 + 3];
    float lc = -num / (den + 1e-6f);
    float smv = accg[384 + b * 2] + accg[385 + b * 2];
    total += lc + lo + 0.01f * smv;
  }
  total *= 0.25f;
  float fsy = 0.f, fsx = 0.f;
  for (int s = 0; s < 16; ++s) { fsy += accg[32 + s * 2]; fsx += accg[33 + s * 2]; }
  const float cnt = 4.f * 384.f * 63.f * 64.f;
  float ly = fsy / cnt * (1.f / 384.f);
  float lx = fsx / cnt * (1.f / 384.f);
  out[131072] = total + 0.09f * 0.5f * (ly + lx);
}

extern "C" void kernel_launch(void* const* d_in, const int* in_sizes, int n_in,
                              void* d_out, int out_size, void* d_ws, size_t ws_size,
                              hipStream_t stream) {
  const float* feat = (const float*)d_in[0];
  const float* gcn_w0 = (const float*)d_in[1];
  const float* gcn_b0 = (const float*)d_in[2];
  const float* gcn_w = (const float*)d_in[3];
  const float* gcn_b = (const float*)d_in[4];
  const float* ln_g = (const float*)d_in[5];
  const float* ln_b = (const float*)d_in[6];
  const float* res_w = (const float*)d_in[7];
  const float* res_b = (const float*)d_in[8];
  const float* res_ln_g = (const float*)d_in[9];
  const float* res_ln_b = (const float*)d_in[10];
  const float* mlp_w1 = (const float*)d_in[11];
  const float* mlp_b1 = (const float*)d_in[12];
  const float* mlp_ln_g = (const float*)d_in[13];
  const float* mlp_ln_b = (const float*)d_in[14];
  const float* mlp_w2 = (const float*)d_in[15];
  const float* mlp_b2 = (const float*)d_in[16];
  const float* sm_w1 = (const float*)d_in[17];
  const float* sm_b1 = (const float*)d_in[18];
  const float* sm_g1 = (const float*)d_in[19];
  const float* sm_bb1 = (const float*)d_in[20];
  const float* sm_w2 = (const float*)d_in[21];
  const float* sm_b2 = (const float*)d_in[22];
  const float* sm_g2 = (const float*)d_in[23];
  const float* sm_bb2 = (const float*)d_in[24];
  const float* ec_w1 = (const float*)d_in[25];
  const float* ec_b1 = (const float*)d_in[26];
  const float* ec_gn_g = (const float*)d_in[27];
  const float* ec_gn_b = (const float*)d_in[28];
  const float* ec_w2 = (const float*)d_in[29];
  const float* ec_b2 = (const float*)d_in[30];

  float* out = (float*)d_out;
  float* ws = (float*)d_ws;
  float* acc = ws;                       // 512 floats
  float* xwA = ws + 512;                 // B*T*64
  float* xwB = xwA + 1048576;            // B*T*64
  float* xbuf = xwB + 1048576;           // B*T*64
  float* resbuf = xbuf + 1048576;        // B*T*64
  float* Sp = resbuf + 1048576;          // B*K*T
  float* eraw = Sp + 131072;             // B*T*32 (pixel-major)
  float* ew = eraw + 524288;             // B*T
  short* wqb = (short*)(ew + 16384);     // 110592 shorts (bf16)
  short* wb = wqb + 110592;              // 49152 shorts (bf16, frag order)
  short* fb = wb + 49152;                // B*T*384 shorts (bf16 feat)
  float* S = out;                        // (B,T,K) straight into d_out

  k_prep<<<3528, 256, 0, stream>>>(feat, ec_w1, gcn_w0, res_w, fb, wqb, wb, acc);

  k_gemm0<<<256, 256, 0, stream>>>(fb, wb, gcn_w0, res_w, res_b, res_ln_g,
                                   res_ln_b, xwA, resbuf);
  // layer 1: stencil0 (resid=resbuf) -> x1 in xbuf; x1@W1 -> xwB
  k_layer<<<512, 256, 0, stream>>>(xwA, gcn_w, gcn_b0, ln_g, ln_b, resbuf, xbuf,
                                   xwB);
  // layer 2: stencil1 (resid=x1 in-place) -> x2; x2@W2 -> xwA
  k_layer<<<512, 256, 0, stream>>>(xwB, gcn_w + 4096, gcn_b, ln_g + 64, ln_b + 64,
                                   xbuf, xbuf, xwA);
  // layer 3: stencil2 -> x3; x3@W3 -> xwB
  k_layer<<<512, 256, 0, stream>>>(xwA, gcn_w + 8192, gcn_b + 64, ln_g + 128,
                                   ln_b + 128, xbuf, xbuf, xwB);
  // layer 4 stencil + MLP head
  k_st4mlp<<<512, 256, 0, stream>>>(xwB, gcn_b + 128, ln_g + 192, ln_b + 192, xbuf,
                                    mlp_w1, mlp_b1, mlp_ln_g, mlp_ln_b, mlp_w2,
                                    mlp_b2, S, Sp);

  k_lossmix<<<800, 256, 0, stream>>>(S, Sp, sm_w1, sm_b1, sm_g1, sm_bb1, sm_w2,
                                     sm_b2, sm_g2, sm_bb2, fb, wqb, ec_b1, eraw,
                                     acc);
  k_ecfinal<<<B_ * T_ / 256, 256, 0, stream>>>(eraw, acc, ec_gn_g, ec_gn_b, ec_w2,
                                               ec_b2, ew);
  k_fsloss<<<512, 256, 0, stream>>>(fb, ew, acc);
  k_final<<<1, 64, 0, stream>>>(acc, out);
}